// Round 5
// baseline (6054.817 us; speedup 1.0000x reference)
//
#include <hip/hip_runtime.h>
#include <cstdint>

typedef _Float16 f16;
typedef _Float16 f16x2 __attribute__((ext_vector_type(2)));

#define T_STEPS 512
#define B_SZ 512
#define LOG2PI 1.8378770664093453f

// raw barrier: drain LDS counters only, never vmcnt (global ops stay in flight)
#define BAR_LDS() asm volatile("s_waitcnt lgkmcnt(0)\n\ts_barrier" ::: "memory")

__device__ __forceinline__ uint32_t packh2(float a, float b) {
  f16x2 v; v[0] = (f16)a; v[1] = (f16)b;
  return __builtin_bit_cast(uint32_t, v);
}

__device__ __forceinline__ float fdot2(uint32_t a, uint32_t b, float c) {
#if defined(__AMDGCN__) && __has_builtin(__builtin_amdgcn_fdot2)
  return __builtin_amdgcn_fdot2(__builtin_bit_cast(f16x2, a),
                                __builtin_bit_cast(f16x2, b), c, false);
#else
  f16x2 x = __builtin_bit_cast(f16x2, a), y = __builtin_bit_cast(f16x2, b);
  return c + (float)x[0] * (float)y[0] + (float)x[1] * (float)y[1];
#endif
}

#define DOT4(acc, w0, w1, w2, w3, v)                                     \
  do {                                                                   \
    acc = fdot2((w0), (v).x, acc); acc = fdot2((w1), (v).y, acc);        \
    acc = fdot2((w2), (v).z, acc); acc = fdot2((w3), (v).w, acc);        \
  } while (0)

__device__ __forceinline__ float sigmoidf_(float x) {
  return 1.0f / (1.0f + __expf(-x));
}
__device__ __forceinline__ float tanhf_(float x) {
  float ax = fabsf(x);
  float t = __expf(-2.0f * ax);
  float r = (1.0f - t) / (1.0f + t);
  return copysignf(r, x);
}
__device__ __forceinline__ float softplusf_(float x) {
  return fmaxf(x, 0.0f) + __logf(1.0f + __expf(-fabsf(x)));
}

// ---------------------------------------------------------------------------
// Kernel 1: embedding / state_t construction.  state_t: (T,B,32) f16.
// ---------------------------------------------------------------------------
__global__ __launch_bounds__(256) void k_embed(
    const float* __restrict__ xs, const float* __restrict__ shot_emb,
    const float* __restrict__ player_emb, f16* __restrict__ state_t,
    float* __restrict__ accums) {
  if (blockIdx.x == 0 && threadIdx.x < 16) accums[threadIdx.x] = 0.0f;
  size_t idx = (size_t)blockIdx.x * 256 + threadIdx.x;
  const float* xp = xs + idx * 23;
  f16* op = state_t + idx * 32;
  int sid = (int)xp[12];
  int pid = (int)xp[17];
#pragma unroll
  for (int i = 0; i < 12; ++i) op[i] = (f16)xp[i];
  const float* se = shot_emb + sid * 8;
#pragma unroll
  for (int i = 0; i < 8; ++i) op[12 + i] = (f16)se[i];
#pragma unroll
  for (int i = 0; i < 4; ++i) op[20 + i] = (f16)xp[13 + i];
  const float* pe = player_emb + pid * 8;
#pragma unroll
  for (int i = 0; i < 8; ++i) op[24 + i] = (f16)pe[i];
}

// ---------------------------------------------------------------------------
// Kernel 2: backward GRU scan + encoder + qz0 head.
// 512 blocks x 256 threads (4 waves), 2 blocks/CU. ONE raw barrier per step.
// Each lane pair (kh=0/1 K-split) owns unit d = wid*32+(lane&31): all three
// gate rows; shuffle-xor-32 combines halves; kh=0 lane updates h (double-
// buffered LDS). kh=1 lanes also compute enc row-halves (shuffle-xor-16),
// storing ctx straight to global (never drained at the raw barrier).
// ---------------------------------------------------------------------------
__global__ __launch_bounds__(256, 2) void k_gru(
    const f16* __restrict__ state_t, const float* __restrict__ wih,
    const float* __restrict__ whh, const float* __restrict__ bih,
    const float* __restrict__ bhh, const float* __restrict__ enc_w,
    const float* __restrict__ enc_b, const float* __restrict__ qz0_w,
    const float* __restrict__ qz0_b, const float* __restrict__ z0_noise,
    const float* __restrict__ pz0_mean, const float* __restrict__ pz0_logstd,
    f16* __restrict__ ctx, float* __restrict__ z0_out,
    float* __restrict__ accums) {
  __shared__ __align__(16) f16 s_hbuf[2][128];
  __shared__ float s_ctx0[64];
  __shared__ float s_q[32];

  const int tid = threadIdx.x;
  const int bg = blockIdx.x;
  const int lane = tid & 63;
  const int wid = tid >> 6;
  const int l31 = lane & 31;
  const int kh = lane >> 5;
  const int d = wid * 32 + l31;
  const int e = wid * 16 + (lane & 15);
  const int eh = (lane >> 4) & 1;
  const uint32_t* stu = (const uint32_t*)state_t;

  uint32_t wR[32], wZ[32], wN[32];
  uint32_t wXR[16], wXZ[16], wXN[16];
  uint32_t wE[32];
  float bR = 0.f, bZ = 0.f, bIN = 0.f, bHN = 0.f, encbr = 0.f;

  {
    const float* r = whh + (size_t)d * 128 + kh * 64;
#pragma unroll
    for (int i = 0; i < 32; ++i) wR[i] = packh2(r[2 * i], r[2 * i + 1]);
    r = whh + (size_t)(128 + d) * 128 + kh * 64;
#pragma unroll
    for (int i = 0; i < 32; ++i) wZ[i] = packh2(r[2 * i], r[2 * i + 1]);
    r = whh + (size_t)(256 + d) * 128 + kh * 64;
#pragma unroll
    for (int i = 0; i < 32; ++i) wN[i] = packh2(r[2 * i], r[2 * i + 1]);
  }
  if (kh == 0) {
    const float* r = wih + (size_t)d * 32;
#pragma unroll
    for (int i = 0; i < 16; ++i) wXR[i] = packh2(r[2 * i], r[2 * i + 1]);
    r = wih + (size_t)(128 + d) * 32;
#pragma unroll
    for (int i = 0; i < 16; ++i) wXZ[i] = packh2(r[2 * i], r[2 * i + 1]);
    r = wih + (size_t)(256 + d) * 32;
#pragma unroll
    for (int i = 0; i < 16; ++i) wXN[i] = packh2(r[2 * i], r[2 * i + 1]);
    bR = bih[d] + bhh[d];
    bZ = bih[128 + d] + bhh[128 + d];
    bIN = bih[256 + d];
    bHN = bhh[256 + d];
  } else {
    const float* r = enc_w + (size_t)e * 128 + eh * 64;
#pragma unroll
    for (int i = 0; i < 32; ++i) wE[i] = packh2(r[2 * i], r[2 * i + 1]);
    encbr = enc_b[e];
  }

  if (tid < 128) s_hbuf[0][tid] = (f16)0.0f;
  float h_old = 0.0f;
  __syncthreads();

  int cur = 0;
  // preload x row for t = 511 (wave-uniform address -> scalar loads)
  uint4 xc0, xc1, xc2, xc3;
  {
    const uint4* xr = (const uint4*)(stu + ((size_t)(T_STEPS - 1) * B_SZ + bg) * 16);
    xc0 = xr[0]; xc1 = xr[1]; xc2 = xr[2]; xc3 = xr[3];
  }

  for (int t = T_STEPS - 1; t >= 0; --t) {
    uint4 xn0, xn1, xn2, xn3;
    if (t > 0) {
      const uint4* xr = (const uint4*)(stu + ((size_t)(t - 1) * B_SZ + bg) * 16);
      xn0 = xr[0]; xn1 = xr[1]; xn2 = xr[2]; xn3 = xr[3];
    }
    float aR = 0.f, aZ = 0.f, aIN = 0.f, aHN = 0.f;
    {
      const uint4* hq = (const uint4*)&s_hbuf[cur][kh * 64];
#pragma unroll
      for (int j = 0; j < 8; ++j) {
        uint4 v = hq[j];
        DOT4(aR, wR[4 * j], wR[4 * j + 1], wR[4 * j + 2], wR[4 * j + 3], v);
        DOT4(aZ, wZ[4 * j], wZ[4 * j + 1], wZ[4 * j + 2], wZ[4 * j + 3], v);
        DOT4(aHN, wN[4 * j], wN[4 * j + 1], wN[4 * j + 2], wN[4 * j + 3], v);
      }
    }
    float enc0 = 0.f, enc1 = 0.f;
    if (kh == 0) {
      DOT4(aR, wXR[0], wXR[1], wXR[2], wXR[3], xc0);
      DOT4(aR, wXR[4], wXR[5], wXR[6], wXR[7], xc1);
      DOT4(aR, wXR[8], wXR[9], wXR[10], wXR[11], xc2);
      DOT4(aR, wXR[12], wXR[13], wXR[14], wXR[15], xc3);
      DOT4(aZ, wXZ[0], wXZ[1], wXZ[2], wXZ[3], xc0);
      DOT4(aZ, wXZ[4], wXZ[5], wXZ[6], wXZ[7], xc1);
      DOT4(aZ, wXZ[8], wXZ[9], wXZ[10], wXZ[11], xc2);
      DOT4(aZ, wXZ[12], wXZ[13], wXZ[14], wXZ[15], xc3);
      DOT4(aIN, wXN[0], wXN[1], wXN[2], wXN[3], xc0);
      DOT4(aIN, wXN[4], wXN[5], wXN[6], wXN[7], xc1);
      DOT4(aIN, wXN[8], wXN[9], wXN[10], wXN[11], xc2);
      DOT4(aIN, wXN[12], wXN[13], wXN[14], wXN[15], xc3);
      aR += bR; aZ += bZ; aIN += bIN; aHN += bHN;
    } else if (t < T_STEPS - 1) {
      const uint4* hq2 = (const uint4*)&s_hbuf[cur][eh * 64];
#pragma unroll
      for (int j = 0; j < 8; ++j) {
        uint4 v = hq2[j];
        if (j & 1) { DOT4(enc1, wE[4 * j], wE[4 * j + 1], wE[4 * j + 2], wE[4 * j + 3], v); }
        else       { DOT4(enc0, wE[4 * j], wE[4 * j + 1], wE[4 * j + 2], wE[4 * j + 3], v); }
      }
    }
    aR += __shfl_xor(aR, 32);
    aZ += __shfl_xor(aZ, 32);
    aHN += __shfl_xor(aHN, 32);
    if (kh == 0) {
      float r = sigmoidf_(aR);
      float zg = sigmoidf_(aZ);
      float n = tanhf_(aIN + r * aHN);
      float hnew = (1.0f - zg) * n + zg * h_old;
      h_old = hnew;
      s_hbuf[cur ^ 1][d] = (f16)hnew;
    } else if (t < T_STEPS - 1) {
      float es = enc0 + enc1;
      es += __shfl_xor(es, 16);
      if (eh == 0)
        ctx[((size_t)(t + 1) * B_SZ + bg) * 64 + e] = (f16)(es + encbr);
    }
    BAR_LDS();
    cur ^= 1;
    if (t > 0) { xc0 = xn0; xc1 = xn1; xc2 = xn2; xc3 = xn3; }
  }

  // ---- Tail: enc(h(0)) -> ctx[0] + s_ctx0; qz0; z0 + KL
  if (kh == 1) {
    float e0 = 0.f, e1 = 0.f;
    const uint4* hq2 = (const uint4*)&s_hbuf[cur][eh * 64];
#pragma unroll
    for (int j = 0; j < 8; ++j) {
      uint4 v = hq2[j];
      if (j & 1) { DOT4(e1, wE[4 * j], wE[4 * j + 1], wE[4 * j + 2], wE[4 * j + 3], v); }
      else       { DOT4(e0, wE[4 * j], wE[4 * j + 1], wE[4 * j + 2], wE[4 * j + 3], v); }
    }
    float es = e0 + e1;
    es += __shfl_xor(es, 16);
    if (eh == 0) {
      float val = es + encbr;
      ctx[(size_t)bg * 64 + e] = (f16)val;
      s_ctx0[e] = val;
    }
  }
  __syncthreads();
  if (tid < 32) {
    float acc = qz0_b[tid];
#pragma unroll 8
    for (int k = 0; k < 64; ++k) acc += qz0_w[tid * 64 + k] * s_ctx0[k];
    s_q[tid] = acc;
  }
  __syncthreads();
  if (tid < 16) {
    float qm = s_q[tid], qls = s_q[16 + tid];
    float z0v = qm + __expf(qls) * z0_noise[bg * 16 + tid];
    z0_out[bg * 16 + tid] = z0v;
    float pm = pz0_mean[tid], pls = pz0_logstd[tid];
    float var_q = __expf(2.0f * qls);
    float var_p = __expf(2.0f * pls);
    float dm = qm - pm;
    float kl = pls - qls + (var_q + dm * dm) / (2.0f * var_p) - 0.5f;
    atomicAdd(&accums[5], kl);
  }
}

// ---------------------------------------------------------------------------
// Kernel 3: SDE scan. 512 blocks x 256 threads, 2 blocks/CU.
// TWO raw barriers per step; wave-synchronous layer chaining:
//  wave0: f1 (z-part + prestaged ctx-partial) -> f2 -> f3 (intra-wave, lgkm
//         waits only); keeps f3 in registers; does phase-2 z update.
//  wave1: h1 -> h2 -> h3 -> s_v3h.
//  wave2: g units 0..63 (shuffle-reduce) -> s_gp[0].
//  wave3: g units 64..127 -> s_gp[1]; also precomputes next step's f1
//         ctx-partial from scalar-prefetched ctx row (double-buffered LDS).
// zs buffered in LDS, flushed once at the end.
// ---------------------------------------------------------------------------
__global__ __launch_bounds__(256, 2) void k_sde(
    const f16* __restrict__ ctx, const float* __restrict__ z0_in,
    const float* __restrict__ ts, const float* __restrict__ bm_noise,
    const float* __restrict__ fw1, const float* __restrict__ fb1,
    const float* __restrict__ fw2, const float* __restrict__ fb2,
    const float* __restrict__ fw3, const float* __restrict__ fb3,
    const float* __restrict__ hw1, const float* __restrict__ hb1,
    const float* __restrict__ hw2, const float* __restrict__ hb2,
    const float* __restrict__ hw3, const float* __restrict__ hb3,
    const float* __restrict__ gw1, const float* __restrict__ gb1,
    const float* __restrict__ gw2, const float* __restrict__ gb2,
    f16* __restrict__ zs, float* __restrict__ accums) {
  __shared__ __align__(16) uint32_t s_x2z[8];   // z packed f16x2
  __shared__ float s_zf[16];                    // z f32
  __shared__ __align__(16) uint32_t s_h1f[64], s_h2f[64];
  __shared__ __align__(16) uint32_t s_h1h[64], s_h2h[64];
  __shared__ __align__(16) float s_pctx[2][128];  // f1 ctx-partial, dbuf
  __shared__ float s_v3h[16];
  __shared__ float s_gp[2][16];
  __shared__ float s_dts[T_STEPS];
  __shared__ __align__(16) f16 s_zbuf[T_STEPS * 16];  // 16 KB

  const int tid = threadIdx.x;
  const int bg = blockIdx.x;
  const int lane = tid & 63;
  const int wid = tid >> 6;

  uint32_t w1[16];   // layer-1 rows (z-part for f; full for h)
  uint32_t w2[128];  // layer-2 two rows
  uint32_t w3[16];   // layer-3 K-quarter slice
  uint32_t wcx[64];  // wave3: f1 ctx-cols, rows 2*lane, 2*lane+1
  float gw1v[16], gb1v[16], gw2v[16];
  float b1a = 0.f, b1b = 0.f, b2a = 0.f, b2b = 0.f, b3r = 0.f, gb2r = 0.f;

  if (wid == 0) {
    const float* r0 = fw1 + (size_t)(2 * lane) * 80;
    const float* r1 = fw1 + (size_t)(2 * lane + 1) * 80;
#pragma unroll
    for (int i = 0; i < 8; ++i) {
      w1[i] = packh2(r0[2 * i], r0[2 * i + 1]);
      w1[8 + i] = packh2(r1[2 * i], r1[2 * i + 1]);
    }
    b1a = fb1[2 * lane]; b1b = fb1[2 * lane + 1];
    r0 = fw2 + (size_t)(2 * lane) * 128;
    r1 = fw2 + (size_t)(2 * lane + 1) * 128;
#pragma unroll
    for (int i = 0; i < 64; ++i) {
      w2[i] = packh2(r0[2 * i], r0[2 * i + 1]);
      w2[64 + i] = packh2(r1[2 * i], r1[2 * i + 1]);
    }
    b2a = fb2[2 * lane]; b2b = fb2[2 * lane + 1];
    {
      int o = lane & 15, q = lane >> 4;
      const float* r3 = fw3 + (size_t)o * 128 + q * 32;
#pragma unroll
      for (int i = 0; i < 16; ++i) w3[i] = packh2(r3[2 * i], r3[2 * i + 1]);
      b3r = fb3[o];
      gb2r = gb2[o];
    }
  } else if (wid == 1) {
    const float* r0 = hw1 + (size_t)(2 * lane) * 16;
    const float* r1 = hw1 + (size_t)(2 * lane + 1) * 16;
#pragma unroll
    for (int i = 0; i < 8; ++i) {
      w1[i] = packh2(r0[2 * i], r0[2 * i + 1]);
      w1[8 + i] = packh2(r1[2 * i], r1[2 * i + 1]);
    }
    b1a = hb1[2 * lane]; b1b = hb1[2 * lane + 1];
    r0 = hw2 + (size_t)(2 * lane) * 128;
    r1 = hw2 + (size_t)(2 * lane + 1) * 128;
#pragma unroll
    for (int i = 0; i < 64; ++i) {
      w2[i] = packh2(r0[2 * i], r0[2 * i + 1]);
      w2[64 + i] = packh2(r1[2 * i], r1[2 * i + 1]);
    }
    b2a = hb2[2 * lane]; b2b = hb2[2 * lane + 1];
    {
      int o = lane & 15, q = lane >> 4;
      const float* r3 = hw3 + (size_t)o * 128 + q * 32;
#pragma unroll
      for (int i = 0; i < 16; ++i) w3[i] = packh2(r3[2 * i], r3[2 * i + 1]);
      b3r = hb3[o];
    }
  } else {
    int l = lane & 15, q = lane >> 4;
    int hbase = (wid - 2) * 64 + q * 16;
#pragma unroll
    for (int j = 0; j < 16; ++j) {
      int h = hbase + j;
      gw1v[j] = gw1[l * 128 + h];
      gb1v[j] = gb1[l * 128 + h];
      gw2v[j] = gw2[l * 128 + h];
    }
    if (wid == 3) {
      const float* r0 = fw1 + (size_t)(2 * lane) * 80 + 16;
      const float* r1 = fw1 + (size_t)(2 * lane + 1) * 80 + 16;
#pragma unroll
      for (int i = 0; i < 32; ++i) {
        wcx[i] = packh2(r0[2 * i], r0[2 * i + 1]);
        wcx[32 + i] = packh2(r1[2 * i], r1[2 * i + 1]);
      }
    }
  }
  for (int i = tid; i < T_STEPS - 1; i += 256) s_dts[i] = ts[i + 1] - ts[i];

  if (tid < 16) {
    float z = z0_in[bg * 16 + tid];
    s_zf[tid] = z;
    s_zbuf[tid] = (f16)z;
  }
  if (tid < 8)
    s_x2z[tid] = packh2(z0_in[bg * 16 + 2 * tid], z0_in[bg * 16 + 2 * tid + 1]);
  float bm_cur = 0.f;
  if (wid == 0 && lane < 16)
    bm_cur = bm_noise[((size_t)0 * B_SZ + bg) * 16 + lane];

  uint4 cc[8];
  if (wid == 3) {
    // pctx for step 0 (uses ctx[1]); preload cc = ctx[2] for step 0's compute
    const uint4* cr =
        (const uint4*)((const uint32_t*)ctx + ((size_t)1 * B_SZ + bg) * 32);
    uint4 a0 = cr[0], a1 = cr[1], a2 = cr[2], a3 = cr[3];
    uint4 a4 = cr[4], a5 = cr[5], a6 = cr[6], a7 = cr[7];
    float p0 = 0.f, p0b = 0.f, p1 = 0.f, p1b = 0.f;
    DOT4(p0, wcx[0], wcx[1], wcx[2], wcx[3], a0);
    DOT4(p0b, wcx[4], wcx[5], wcx[6], wcx[7], a1);
    DOT4(p0, wcx[8], wcx[9], wcx[10], wcx[11], a2);
    DOT4(p0b, wcx[12], wcx[13], wcx[14], wcx[15], a3);
    DOT4(p0, wcx[16], wcx[17], wcx[18], wcx[19], a4);
    DOT4(p0b, wcx[20], wcx[21], wcx[22], wcx[23], a5);
    DOT4(p0, wcx[24], wcx[25], wcx[26], wcx[27], a6);
    DOT4(p0b, wcx[28], wcx[29], wcx[30], wcx[31], a7);
    DOT4(p1, wcx[32], wcx[33], wcx[34], wcx[35], a0);
    DOT4(p1b, wcx[36], wcx[37], wcx[38], wcx[39], a1);
    DOT4(p1, wcx[40], wcx[41], wcx[42], wcx[43], a2);
    DOT4(p1b, wcx[44], wcx[45], wcx[46], wcx[47], a3);
    DOT4(p1, wcx[48], wcx[49], wcx[50], wcx[51], a4);
    DOT4(p1b, wcx[52], wcx[53], wcx[54], wcx[55], a5);
    DOT4(p1, wcx[56], wcx[57], wcx[58], wcx[59], a6);
    DOT4(p1b, wcx[60], wcx[61], wcx[62], wcx[63], a7);
    *(float2*)&s_pctx[0][2 * lane] = make_float2(p0 + p0b, p1 + p1b);
    const uint4* c2 =
        (const uint4*)((const uint32_t*)ctx + ((size_t)2 * B_SZ + bg) * 32);
#pragma unroll
    for (int i = 0; i < 8; ++i) cc[i] = c2[i];
  }
  float path_acc = 0.0f;
  float fv_r = 0.0f;
  __syncthreads();

  for (int t = 0; t < T_STEPS - 1; ++t) {
    // ================= Phase 1 =================
    if (wid == 0) {
      const uint4* zq = (const uint4*)s_x2z;
      uint4 zv0 = zq[0], zv1 = zq[1];
      float2 pc = *(const float2*)&s_pctx[t & 1][2 * lane];
      float a0 = b1a + pc.x, a1 = b1b + pc.y;
      DOT4(a0, w1[0], w1[1], w1[2], w1[3], zv0);
      DOT4(a0, w1[4], w1[5], w1[6], w1[7], zv1);
      DOT4(a1, w1[8], w1[9], w1[10], w1[11], zv0);
      DOT4(a1, w1[12], w1[13], w1[14], w1[15], zv1);
      s_h1f[lane] = packh2(softplusf_(a0), softplusf_(a1));
      // f2 (intra-wave: lgkm wait only)
      const uint4* hq = (const uint4*)s_h1f;
      float c0 = b2a, c0b = 0.f, c1 = b2b, c1b = 0.f;
#pragma unroll
      for (int j = 0; j < 16; ++j) {
        uint4 v = hq[j];
        if (j & 1) {
          DOT4(c0b, w2[4 * j], w2[4 * j + 1], w2[4 * j + 2], w2[4 * j + 3], v);
          DOT4(c1b, w2[64 + 4 * j], w2[65 + 4 * j], w2[66 + 4 * j], w2[67 + 4 * j], v);
        } else {
          DOT4(c0, w2[4 * j], w2[4 * j + 1], w2[4 * j + 2], w2[4 * j + 3], v);
          DOT4(c1, w2[64 + 4 * j], w2[65 + 4 * j], w2[66 + 4 * j], w2[67 + 4 * j], v);
        }
      }
      s_h2f[lane] = packh2(softplusf_(c0 + c0b), softplusf_(c1 + c1b));
      // f3 (intra-wave)
      {
        int q = lane >> 4;
        const uint4* h2q = (const uint4*)&s_h2f[q * 16];
        uint4 v0 = h2q[0], v1 = h2q[1], v2 = h2q[2], v3 = h2q[3];
        float f3 = 0.f, f3b = 0.f;
        DOT4(f3, w3[0], w3[1], w3[2], w3[3], v0);
        DOT4(f3b, w3[4], w3[5], w3[6], w3[7], v1);
        DOT4(f3, w3[8], w3[9], w3[10], w3[11], v2);
        DOT4(f3b, w3[12], w3[13], w3[14], w3[15], v3);
        f3 += f3b;
        f3 += __shfl_xor(f3, 16);
        f3 += __shfl_xor(f3, 32);
        fv_r = f3 + b3r;  // valid on lanes 0-15
      }
    } else if (wid == 1) {
      const uint4* zq = (const uint4*)s_x2z;
      uint4 zv0 = zq[0], zv1 = zq[1];
      float a0 = b1a, a1 = b1b;
      DOT4(a0, w1[0], w1[1], w1[2], w1[3], zv0);
      DOT4(a0, w1[4], w1[5], w1[6], w1[7], zv1);
      DOT4(a1, w1[8], w1[9], w1[10], w1[11], zv0);
      DOT4(a1, w1[12], w1[13], w1[14], w1[15], zv1);
      s_h1h[lane] = packh2(softplusf_(a0), softplusf_(a1));
      const uint4* hq = (const uint4*)s_h1h;
      float c0 = b2a, c0b = 0.f, c1 = b2b, c1b = 0.f;
#pragma unroll
      for (int j = 0; j < 16; ++j) {
        uint4 v = hq[j];
        if (j & 1) {
          DOT4(c0b, w2[4 * j], w2[4 * j + 1], w2[4 * j + 2], w2[4 * j + 3], v);
          DOT4(c1b, w2[64 + 4 * j], w2[65 + 4 * j], w2[66 + 4 * j], w2[67 + 4 * j], v);
        } else {
          DOT4(c0, w2[4 * j], w2[4 * j + 1], w2[4 * j + 2], w2[4 * j + 3], v);
          DOT4(c1, w2[64 + 4 * j], w2[65 + 4 * j], w2[66 + 4 * j], w2[67 + 4 * j], v);
        }
      }
      s_h2h[lane] = packh2(softplusf_(c0 + c0b), softplusf_(c1 + c1b));
      {
        int q = lane >> 4;
        const uint4* h2q = (const uint4*)&s_h2h[q * 16];
        uint4 v0 = h2q[0], v1 = h2q[1], v2 = h2q[2], v3 = h2q[3];
        float h3 = 0.f, h3b = 0.f;
        DOT4(h3, w3[0], w3[1], w3[2], w3[3], v0);
        DOT4(h3b, w3[4], w3[5], w3[6], w3[7], v1);
        DOT4(h3, w3[8], w3[9], w3[10], w3[11], v2);
        DOT4(h3b, w3[12], w3[13], w3[14], w3[15], v3);
        h3 += h3b;
        h3 += __shfl_xor(h3, 16);
        h3 += __shfl_xor(h3, 32);
        if (lane < 16) s_v3h[lane] = h3 + b3r;
      }
    } else {
      int l = lane & 15;
      float y = s_zf[l];
      float acc = 0.f;
#pragma unroll
      for (int j = 0; j < 16; ++j) {
        float pre = fmaf(y, gw1v[j], gb1v[j]);
        acc = fmaf(softplusf_(pre), gw2v[j], acc);
      }
      acc += __shfl_xor(acc, 16);
      acc += __shfl_xor(acc, 32);
      if (lane < 16) s_gp[wid - 2][l] = acc;
      if (wid == 3) {
        if (t <= T_STEPS - 3) {
          float p0 = 0.f, p0b = 0.f, p1 = 0.f, p1b = 0.f;
          DOT4(p0, wcx[0], wcx[1], wcx[2], wcx[3], cc[0]);
          DOT4(p0b, wcx[4], wcx[5], wcx[6], wcx[7], cc[1]);
          DOT4(p0, wcx[8], wcx[9], wcx[10], wcx[11], cc[2]);
          DOT4(p0b, wcx[12], wcx[13], wcx[14], wcx[15], cc[3]);
          DOT4(p0, wcx[16], wcx[17], wcx[18], wcx[19], cc[4]);
          DOT4(p0b, wcx[20], wcx[21], wcx[22], wcx[23], cc[5]);
          DOT4(p0, wcx[24], wcx[25], wcx[26], wcx[27], cc[6]);
          DOT4(p0b, wcx[28], wcx[29], wcx[30], wcx[31], cc[7]);
          DOT4(p1, wcx[32], wcx[33], wcx[34], wcx[35], cc[0]);
          DOT4(p1b, wcx[36], wcx[37], wcx[38], wcx[39], cc[1]);
          DOT4(p1, wcx[40], wcx[41], wcx[42], wcx[43], cc[2]);
          DOT4(p1b, wcx[44], wcx[45], wcx[46], wcx[47], cc[3]);
          DOT4(p1, wcx[48], wcx[49], wcx[50], wcx[51], cc[4]);
          DOT4(p1b, wcx[52], wcx[53], wcx[54], wcx[55], cc[5]);
          DOT4(p1, wcx[56], wcx[57], wcx[58], wcx[59], cc[6]);
          DOT4(p1b, wcx[60], wcx[61], wcx[62], wcx[63], cc[7]);
          *(float2*)&s_pctx[(t + 1) & 1][2 * lane] =
              make_float2(p0 + p0b, p1 + p1b);
        }
        if (t <= T_STEPS - 4) {
          const uint4* cr = (const uint4*)((const uint32_t*)ctx +
                                           ((size_t)(t + 3) * B_SZ + bg) * 32);
#pragma unroll
          for (int i = 0; i < 8; ++i) cc[i] = cr[i];
        }
      }
    }
    BAR_LDS();
    // ================= Phase 2 (wave0 lanes 0-15) =================
    if (wid == 0 && lane < 16) {
      int l = lane;
      float hv = s_v3h[l];
      float gv = sigmoidf_(gb2r + s_gp[0][l] + s_gp[1][l]);
      float dt = s_dts[t];
      float uu = (fv_r - hv) / gv;
      float lsum = uu * uu;
      lsum += __shfl_xor(lsum, 1);
      lsum += __shfl_xor(lsum, 2);
      lsum += __shfl_xor(lsum, 4);
      lsum += __shfl_xor(lsum, 8);
      if (l == 0) path_acc += 0.5f * lsum * dt;
      float zn = s_zf[l] + fv_r * dt + gv * (sqrtf(dt) * bm_cur);
      s_zf[l] = zn;
      s_zbuf[(t + 1) * 16 + l] = (f16)zn;
      float zo = __shfl_xor(zn, 1);
      if (!(l & 1)) s_x2z[l >> 1] = packh2(zn, zo);
      if (t < T_STEPS - 2)
        bm_cur = bm_noise[((size_t)(t + 1) * B_SZ + bg) * 16 + l];
    }
    BAR_LDS();
  }
  if (wid == 0 && lane == 0) atomicAdd(&accums[6], path_acc);
  // flush zs buffer (512 rows x 32 B)
#pragma unroll
  for (int it = 0; it < 4; ++it) {
    int idx = it * 256 + tid;
    int row = idx >> 1, half = idx & 1;
    uint4 v = *(const uint4*)((const uint32_t*)s_zbuf + row * 8 + half * 4);
    *(uint4*)((uint32_t*)zs + ((size_t)row * B_SZ + bg) * 8 + half * 4) = v;
  }
}

// ---------------------------------------------------------------------------
// Kernel 4: decoder + losses.  2 tokens per thread, uint4 LDS layouts.
// ---------------------------------------------------------------------------
__global__ __launch_bounds__(256) void k_dec(
    const f16* __restrict__ zs, const f16* __restrict__ state_t,
    const float* __restrict__ xs, const float* __restrict__ proj_w,
    const float* __restrict__ proj_b, const float* __restrict__ act_w,
    const float* __restrict__ act_b, const float* __restrict__ land_w,
    const float* __restrict__ shot_w, const float* __restrict__ move_w,
    float* __restrict__ accums) {
  __shared__ __align__(16) uint32_t s_proj[32 * 8];
  __shared__ __align__(16) uint32_t s_act[128 * 8];
  __shared__ __align__(16) uint32_t s_head[128 * 8];
  __shared__ float s_pb[32], s_ab[128];
  __shared__ float s_red[4 * 5];

  const int tid = threadIdx.x;
  if (tid < 256) {
    int i = tid >> 3, kp = tid & 7;
    s_proj[tid] = packh2(proj_w[i * 16 + 2 * kp], proj_w[i * 16 + 2 * kp + 1]);
  }
  for (int id = tid; id < 1024; id += 256) {
    int j = id >> 3, kp = id & 7;
    s_act[id] = packh2(act_w[j * 16 + 2 * kp], act_w[j * 16 + 2 * kp + 1]);
  }
  for (int id = tid; id < 1024; id += 256) {
    int j = id >> 3, p = id & 7;
    int h0 = 2 * p, h1 = 2 * p + 1;
    float w0 = (h0 < 2) ? land_w[h0 * 128 + j]
                        : (h0 < 14 ? shot_w[(h0 - 2) * 128 + j]
                                   : move_w[(h0 - 14) * 128 + j]);
    float w1 = (h1 < 2) ? land_w[h1 * 128 + j]
                        : (h1 < 14 ? shot_w[(h1 - 2) * 128 + j]
                                   : move_w[(h1 - 14) * 128 + j]);
    s_head[j * 8 + p] = packh2(w0, w1);
  }
  if (tid < 32) s_pb[tid] = proj_b[tid];
  if (tid < 128) s_ab[tid] = act_b[tid];
  __syncthreads();

  size_t idx0 = (size_t)blockIdx.x * 512 + tid;
  size_t idx1 = idx0 + 256;
  uint32_t zA[8], zB[8];
  {
    const uint4* za = (const uint4*)(zs + idx0 * 16);
    const uint4* zb = (const uint4*)(zs + idx1 * 16);
    uint4 a0 = za[0], a1 = za[1], b0 = zb[0], b1 = zb[1];
    zA[0] = a0.x; zA[1] = a0.y; zA[2] = a0.z; zA[3] = a0.w;
    zA[4] = a1.x; zA[5] = a1.y; zA[6] = a1.z; zA[7] = a1.w;
    zB[0] = b0.x; zB[1] = b0.y; zB[2] = b0.z; zB[3] = b0.w;
    zB[4] = b1.x; zB[5] = b1.y; zB[6] = b1.z; zB[7] = b1.w;
  }
  uint32_t stA[16], stB[16];
  {
    const uint4* sa = (const uint4*)(state_t + idx0 * 32);
    const uint4* sb = (const uint4*)(state_t + idx1 * 32);
#pragma unroll
    for (int q = 0; q < 4; ++q) {
      uint4 va = sa[q], vb = sb[q];
      stA[4 * q] = va.x; stA[4 * q + 1] = va.y; stA[4 * q + 2] = va.z; stA[4 * q + 3] = va.w;
      stB[4 * q] = vb.x; stB[4 * q + 1] = vb.y; stB[4 * q + 2] = vb.z; stB[4 * q + 3] = vb.w;
    }
  }

  float sqA = 0.0f, sqB = 0.0f;
#pragma unroll 4
  for (int i = 0; i < 32; ++i) {
    const uint4* pw = (const uint4*)&s_proj[i * 8];
    uint4 w0 = pw[0], w1 = pw[1];
    float aA = s_pb[i], aB = s_pb[i];
    DOT4(aA, w0.x, w0.y, w0.z, w0.w, *(const uint4*)&zA[0]);
    DOT4(aA, w1.x, w1.y, w1.z, w1.w, *(const uint4*)&zA[4]);
    DOT4(aB, w0.x, w0.y, w0.z, w0.w, *(const uint4*)&zB[0]);
    DOT4(aB, w1.x, w1.y, w1.z, w1.w, *(const uint4*)&zB[4]);
    f16x2 svA = __builtin_bit_cast(f16x2, stA[i >> 1]);
    f16x2 svB = __builtin_bit_cast(f16x2, stB[i >> 1]);
    float dA = (float)svA[i & 1] - aA;
    float dB = (float)svB[i & 1] - aB;
    sqA += dA * dA;
    sqB += dB * dB;
  }

  float hdA[16], hdB[16];
#pragma unroll
  for (int i = 0; i < 16; ++i) { hdA[i] = 0.0f; hdB[i] = 0.0f; }
#pragma unroll 2
  for (int j = 0; j < 128; ++j) {
    const uint4* aw = (const uint4*)&s_act[j * 8];
    uint4 w0 = aw[0], w1 = aw[1];
    float aA = s_ab[j], aB = s_ab[j];
    DOT4(aA, w0.x, w0.y, w0.z, w0.w, *(const uint4*)&zA[0]);
    DOT4(aA, w1.x, w1.y, w1.z, w1.w, *(const uint4*)&zA[4]);
    DOT4(aB, w0.x, w0.y, w0.z, w0.w, *(const uint4*)&zB[0]);
    DOT4(aB, w1.x, w1.y, w1.z, w1.w, *(const uint4*)&zB[4]);
    aA = fmaxf(aA, 0.0f);
    aB = fmaxf(aB, 0.0f);
    const uint4* hw = (const uint4*)&s_head[j * 8];
    uint4 h0 = hw[0], h1 = hw[1];
    uint32_t whu[8] = {h0.x, h0.y, h0.z, h0.w, h1.x, h1.y, h1.z, h1.w};
#pragma unroll
    for (int p = 0; p < 8; ++p) {
      f16x2 w = __builtin_bit_cast(f16x2, whu[p]);
      float w0f = (float)w[0], w1f = (float)w[1];
      hdA[2 * p] += w0f * aA;
      hdA[2 * p + 1] += w1f * aA;
      hdB[2 * p] += w0f * aB;
      hdB[2 * p + 1] += w1f * aB;
    }
  }

  float vals[5] = {sqA + sqB, 0.f, 0.f, 0.f, 0.f};
#pragma unroll
  for (int tok = 0; tok < 2; ++tok) {
    const float* hd = tok ? hdB : hdA;
    const float* xp = xs + (tok ? idx1 : idx0) * 23;
    float dl0 = hd[0] - xp[18], dl1 = hd[1] - xp[19];
    vals[1] += dl0 * dl0 + dl1 * dl1;
    float dm0 = hd[14] - xp[21], dm1 = hd[15] - xp[22];
    vals[2] += dm0 * dm0 + dm1 * dm1;
    int sid = (int)xp[20];
    float m = hd[2];
#pragma unroll
    for (int s = 1; s < 12; ++s) m = fmaxf(m, hd[2 + s]);
    float sume = 0.0f;
#pragma unroll
    for (int s = 0; s < 12; ++s) sume += __expf(hd[2 + s] - m);
    float lse = m + __logf(sume);
    float pl = 0.0f;
#pragma unroll
    for (int s = 0; s < 12; ++s)
      if (s == sid) pl = hd[2 + s];
    if (sid != 0) {
      vals[3] += pl - lse;
      vals[4] += 1.0f;
    }
  }
#pragma unroll
  for (int v = 0; v < 5; ++v) {
    float x = vals[v];
    for (int off = 1; off < 64; off <<= 1) x += __shfl_xor(x, off);
    vals[v] = x;
  }
  int lane = tid & 63, wv = tid >> 6;
  if (lane == 0) {
#pragma unroll
    for (int v = 0; v < 5; ++v) s_red[wv * 5 + v] = vals[v];
  }
  __syncthreads();
  if (tid == 0) {
#pragma unroll
    for (int v = 0; v < 5; ++v) {
      float s = s_red[v] + s_red[5 + v] + s_red[10 + v] + s_red[15 + v];
      atomicAdd(&accums[v], s);
    }
  }
}

// ---------------------------------------------------------------------------
// Kernel 5: finalize the two scalar outputs.
// ---------------------------------------------------------------------------
__global__ void k_fin(const float* __restrict__ accums,
                      const float* __restrict__ noise_std,
                      float* __restrict__ out) {
  if (threadIdx.x == 0 && blockIdx.x == 0) {
    float sd = noise_std[0];
    float log_pxs = -0.5f * accums[0] / (sd * sd * (float)B_SZ) -
                    (float)T_STEPS * 32.0f * (logf(sd) + 0.5f * LOG2PI);
    float land = accums[1] / (float)(T_STEPS * B_SZ * 2);
    float move = accums[2] / (float)(T_STEPS * B_SZ * 2);
    float shot = -accums[3] / fmaxf(accums[4], 1.0f);
    float out1 = accums[5] / (float)B_SZ + accums[6] / (float)B_SZ + land + shot + move;
    out[0] = log_pxs;
    out[1] = out1;
  }
}

// ---------------------------------------------------------------------------
extern "C" void kernel_launch(void* const* d_in, const int* in_sizes, int n_in,
                              void* d_out, int out_size, void* d_ws,
                              size_t ws_size, hipStream_t stream) {
  const float* xs = (const float*)d_in[1];
  const float* ts = (const float*)d_in[2];
  const float* noise_std = (const float*)d_in[3];
  const float* z0_noise = (const float*)d_in[4];
  const float* bm_noise = (const float*)d_in[5];
  const float* shot_emb = (const float*)d_in[6];
  const float* player_emb = (const float*)d_in[7];
  const float* gru_wih = (const float*)d_in[8];
  const float* gru_whh = (const float*)d_in[9];
  const float* gru_bih = (const float*)d_in[10];
  const float* gru_bhh = (const float*)d_in[11];
  const float* enc_w = (const float*)d_in[12];
  const float* enc_b = (const float*)d_in[13];
  const float* qz0_w = (const float*)d_in[14];
  const float* qz0_b = (const float*)d_in[15];
  const float* f_w1 = (const float*)d_in[16];
  const float* f_b1 = (const float*)d_in[17];
  const float* f_w2 = (const float*)d_in[18];
  const float* f_b2 = (const float*)d_in[19];
  const float* f_w3 = (const float*)d_in[20];
  const float* f_b3 = (const float*)d_in[21];
  const float* h_w1 = (const float*)d_in[22];
  const float* h_b1 = (const float*)d_in[23];
  const float* h_w2 = (const float*)d_in[24];
  const float* h_b2 = (const float*)d_in[25];
  const float* h_w3 = (const float*)d_in[26];
  const float* h_b3 = (const float*)d_in[27];
  const float* g_w1 = (const float*)d_in[28];
  const float* g_b1 = (const float*)d_in[29];
  const float* g_w2 = (const float*)d_in[30];
  const float* g_b2 = (const float*)d_in[31];
  const float* proj_w = (const float*)d_in[32];
  const float* proj_b = (const float*)d_in[33];
  const float* pz0_mean = (const float*)d_in[34];
  const float* pz0_logstd = (const float*)d_in[35];
  const float* act_w = (const float*)d_in[36];
  const float* act_b = (const float*)d_in[37];
  const float* act_land_w = (const float*)d_in[38];
  const float* act_shot_w = (const float*)d_in[39];
  const float* act_move_w = (const float*)d_in[40];

  char* ws = (char*)d_ws;
  float* accums = (float*)ws;                       // 16 floats
  f16* state_t = (f16*)(ws + 256);                  // T*B*32 f16 = 16 MB
  f16* ctx = (f16*)(ws + 256 + 16777216);           // T*B*64 f16 = 32 MB
  float* z0b = (float*)(ws + 256 + 16777216 + 33554432);   // B*16 f32
  f16* zs = (f16*)(ws + 256 + 16777216 + 33554432 + 32768);  // T*B*16 f16 = 8 MB

  k_embed<<<1024, 256, 0, stream>>>(xs, shot_emb, player_emb, state_t, accums);
  k_gru<<<512, 256, 0, stream>>>(state_t, gru_wih, gru_whh, gru_bih, gru_bhh,
                                 enc_w, enc_b, qz0_w, qz0_b, z0_noise, pz0_mean,
                                 pz0_logstd, ctx, z0b, accums);
  k_sde<<<512, 256, 0, stream>>>(ctx, z0b, ts, bm_noise, f_w1, f_b1, f_w2, f_b2,
                                 f_w3, f_b3, h_w1, h_b1, h_w2, h_b2, h_w3, h_b3,
                                 g_w1, g_b1, g_w2, g_b2, zs, accums);
  k_dec<<<512, 256, 0, stream>>>(zs, state_t, xs, proj_w, proj_b, act_w, act_b,
                                 act_land_w, act_shot_w, act_move_w, accums);
  k_fin<<<1, 64, 0, stream>>>(accums, noise_std, (float*)d_out);
}

// Round 6
// 2146.971 us; speedup vs baseline: 2.8202x; 2.8202x over previous
//
#include <hip/hip_runtime.h>
#include <cstdint>

typedef _Float16 f16;
typedef _Float16 f16x2 __attribute__((ext_vector_type(2)));

#define T_STEPS 512
#define B_SZ 512
#define LOG2PI 1.8378770664093453f

// raw barrier: drain LDS counters only, never vmcnt (global ops stay in flight)
#define BAR_LDS() asm volatile("s_waitcnt lgkmcnt(0)\n\ts_barrier" ::: "memory")

__device__ __forceinline__ uint32_t packh2(float a, float b) {
  f16x2 v; v[0] = (f16)a; v[1] = (f16)b;
  return __builtin_bit_cast(uint32_t, v);
}

__device__ __forceinline__ float fdot2(uint32_t a, uint32_t b, float c) {
#if defined(__AMDGCN__) && __has_builtin(__builtin_amdgcn_fdot2)
  return __builtin_amdgcn_fdot2(__builtin_bit_cast(f16x2, a),
                                __builtin_bit_cast(f16x2, b), c, false);
#else
  f16x2 x = __builtin_bit_cast(f16x2, a), y = __builtin_bit_cast(f16x2, b);
  return c + (float)x[0] * (float)y[0] + (float)x[1] * (float)y[1];
#endif
}

#define DOT4(acc, w0, w1, w2, w3, v)                                     \
  do {                                                                   \
    acc = fdot2((w0), (v).x, acc); acc = fdot2((w1), (v).y, acc);        \
    acc = fdot2((w2), (v).z, acc); acc = fdot2((w3), (v).w, acc);        \
  } while (0)

__device__ __forceinline__ float sigmoidf_(float x) {
  return 1.0f / (1.0f + __expf(-x));
}
__device__ __forceinline__ float tanhf_(float x) {
  float ax = fabsf(x);
  float t = __expf(-2.0f * ax);
  float r = (1.0f - t) / (1.0f + t);
  return copysignf(r, x);
}
__device__ __forceinline__ float softplusf_(float x) {
  return fmaxf(x, 0.0f) + __logf(1.0f + __expf(-fabsf(x)));
}

// ---------------------------------------------------------------------------
// Kernel 1: embedding / state_t construction.  state_t: (T,B,32) f16.
// ---------------------------------------------------------------------------
__global__ __launch_bounds__(256) void k_embed(
    const float* __restrict__ xs, const float* __restrict__ shot_emb,
    const float* __restrict__ player_emb, f16* __restrict__ state_t,
    float* __restrict__ accums) {
  if (blockIdx.x == 0 && threadIdx.x < 16) accums[threadIdx.x] = 0.0f;
  size_t idx = (size_t)blockIdx.x * 256 + threadIdx.x;
  const float* xp = xs + idx * 23;
  f16* op = state_t + idx * 32;
  int sid = (int)xp[12];
  int pid = (int)xp[17];
#pragma unroll
  for (int i = 0; i < 12; ++i) op[i] = (f16)xp[i];
  const float* se = shot_emb + sid * 8;
#pragma unroll
  for (int i = 0; i < 8; ++i) op[12 + i] = (f16)se[i];
#pragma unroll
  for (int i = 0; i < 4; ++i) op[20 + i] = (f16)xp[13 + i];
  const float* pe = player_emb + pid * 8;
#pragma unroll
  for (int i = 0; i < 8; ++i) op[24 + i] = (f16)pe[i];
}

// ---------------------------------------------------------------------------
// Kernel 2: backward GRU scan + encoder + qz0 head.  (R5 design - verified.)
// 512 blocks x 256 threads (4 waves), 2 blocks/CU. ONE raw barrier per step.
// ---------------------------------------------------------------------------
__global__ __launch_bounds__(256, 2) void k_gru(
    const f16* __restrict__ state_t, const float* __restrict__ wih,
    const float* __restrict__ whh, const float* __restrict__ bih,
    const float* __restrict__ bhh, const float* __restrict__ enc_w,
    const float* __restrict__ enc_b, const float* __restrict__ qz0_w,
    const float* __restrict__ qz0_b, const float* __restrict__ z0_noise,
    const float* __restrict__ pz0_mean, const float* __restrict__ pz0_logstd,
    f16* __restrict__ ctx, float* __restrict__ z0_out,
    float* __restrict__ accums) {
  __shared__ __align__(16) f16 s_hbuf[2][128];
  __shared__ float s_ctx0[64];
  __shared__ float s_q[32];

  const int tid = threadIdx.x;
  const int bg = blockIdx.x;
  const int lane = tid & 63;
  const int wid = tid >> 6;
  const int l31 = lane & 31;
  const int kh = lane >> 5;
  const int d = wid * 32 + l31;
  const int e = wid * 16 + (lane & 15);
  const int eh = (lane >> 4) & 1;
  const uint32_t* stu = (const uint32_t*)state_t;

  uint32_t wR[32], wZ[32], wN[32];
  uint32_t wXR[16], wXZ[16], wXN[16];
  uint32_t wE[32];
  float bR = 0.f, bZ = 0.f, bIN = 0.f, bHN = 0.f, encbr = 0.f;

  {
    const float* r = whh + (size_t)d * 128 + kh * 64;
#pragma unroll
    for (int i = 0; i < 32; ++i) wR[i] = packh2(r[2 * i], r[2 * i + 1]);
    r = whh + (size_t)(128 + d) * 128 + kh * 64;
#pragma unroll
    for (int i = 0; i < 32; ++i) wZ[i] = packh2(r[2 * i], r[2 * i + 1]);
    r = whh + (size_t)(256 + d) * 128 + kh * 64;
#pragma unroll
    for (int i = 0; i < 32; ++i) wN[i] = packh2(r[2 * i], r[2 * i + 1]);
  }
  if (kh == 0) {
    const float* r = wih + (size_t)d * 32;
#pragma unroll
    for (int i = 0; i < 16; ++i) wXR[i] = packh2(r[2 * i], r[2 * i + 1]);
    r = wih + (size_t)(128 + d) * 32;
#pragma unroll
    for (int i = 0; i < 16; ++i) wXZ[i] = packh2(r[2 * i], r[2 * i + 1]);
    r = wih + (size_t)(256 + d) * 32;
#pragma unroll
    for (int i = 0; i < 16; ++i) wXN[i] = packh2(r[2 * i], r[2 * i + 1]);
    bR = bih[d] + bhh[d];
    bZ = bih[128 + d] + bhh[128 + d];
    bIN = bih[256 + d];
    bHN = bhh[256 + d];
  } else {
    const float* r = enc_w + (size_t)e * 128 + eh * 64;
#pragma unroll
    for (int i = 0; i < 32; ++i) wE[i] = packh2(r[2 * i], r[2 * i + 1]);
    encbr = enc_b[e];
  }

  if (tid < 128) s_hbuf[0][tid] = (f16)0.0f;
  float h_old = 0.0f;
  __syncthreads();

  int cur = 0;
  uint4 xc0, xc1, xc2, xc3;
  {
    const uint4* xr = (const uint4*)(stu + ((size_t)(T_STEPS - 1) * B_SZ + bg) * 16);
    xc0 = xr[0]; xc1 = xr[1]; xc2 = xr[2]; xc3 = xr[3];
  }

  for (int t = T_STEPS - 1; t >= 0; --t) {
    uint4 xn0, xn1, xn2, xn3;
    if (t > 0) {
      const uint4* xr = (const uint4*)(stu + ((size_t)(t - 1) * B_SZ + bg) * 16);
      xn0 = xr[0]; xn1 = xr[1]; xn2 = xr[2]; xn3 = xr[3];
    }
    float aR = 0.f, aZ = 0.f, aIN = 0.f, aHN = 0.f;
    {
      const uint4* hq = (const uint4*)&s_hbuf[cur][kh * 64];
#pragma unroll
      for (int j = 0; j < 8; ++j) {
        uint4 v = hq[j];
        DOT4(aR, wR[4 * j], wR[4 * j + 1], wR[4 * j + 2], wR[4 * j + 3], v);
        DOT4(aZ, wZ[4 * j], wZ[4 * j + 1], wZ[4 * j + 2], wZ[4 * j + 3], v);
        DOT4(aHN, wN[4 * j], wN[4 * j + 1], wN[4 * j + 2], wN[4 * j + 3], v);
      }
    }
    float enc0 = 0.f, enc1 = 0.f;
    if (kh == 0) {
      DOT4(aR, wXR[0], wXR[1], wXR[2], wXR[3], xc0);
      DOT4(aR, wXR[4], wXR[5], wXR[6], wXR[7], xc1);
      DOT4(aR, wXR[8], wXR[9], wXR[10], wXR[11], xc2);
      DOT4(aR, wXR[12], wXR[13], wXR[14], wXR[15], xc3);
      DOT4(aZ, wXZ[0], wXZ[1], wXZ[2], wXZ[3], xc0);
      DOT4(aZ, wXZ[4], wXZ[5], wXZ[6], wXZ[7], xc1);
      DOT4(aZ, wXZ[8], wXZ[9], wXZ[10], wXZ[11], xc2);
      DOT4(aZ, wXZ[12], wXZ[13], wXZ[14], wXZ[15], xc3);
      DOT4(aIN, wXN[0], wXN[1], wXN[2], wXN[3], xc0);
      DOT4(aIN, wXN[4], wXN[5], wXN[6], wXN[7], xc1);
      DOT4(aIN, wXN[8], wXN[9], wXN[10], wXN[11], xc2);
      DOT4(aIN, wXN[12], wXN[13], wXN[14], wXN[15], xc3);
      aR += bR; aZ += bZ; aIN += bIN; aHN += bHN;
    } else if (t < T_STEPS - 1) {
      const uint4* hq2 = (const uint4*)&s_hbuf[cur][eh * 64];
#pragma unroll
      for (int j = 0; j < 8; ++j) {
        uint4 v = hq2[j];
        if (j & 1) { DOT4(enc1, wE[4 * j], wE[4 * j + 1], wE[4 * j + 2], wE[4 * j + 3], v); }
        else       { DOT4(enc0, wE[4 * j], wE[4 * j + 1], wE[4 * j + 2], wE[4 * j + 3], v); }
      }
    }
    aR += __shfl_xor(aR, 32);
    aZ += __shfl_xor(aZ, 32);
    aHN += __shfl_xor(aHN, 32);
    if (kh == 0) {
      float r = sigmoidf_(aR);
      float zg = sigmoidf_(aZ);
      float n = tanhf_(aIN + r * aHN);
      float hnew = (1.0f - zg) * n + zg * h_old;
      h_old = hnew;
      s_hbuf[cur ^ 1][d] = (f16)hnew;
    } else if (t < T_STEPS - 1) {
      float es = enc0 + enc1;
      es += __shfl_xor(es, 16);
      if (eh == 0)
        ctx[((size_t)(t + 1) * B_SZ + bg) * 64 + e] = (f16)(es + encbr);
    }
    BAR_LDS();
    cur ^= 1;
    if (t > 0) { xc0 = xn0; xc1 = xn1; xc2 = xn2; xc3 = xn3; }
  }

  if (kh == 1) {
    float e0 = 0.f, e1 = 0.f;
    const uint4* hq2 = (const uint4*)&s_hbuf[cur][eh * 64];
#pragma unroll
    for (int j = 0; j < 8; ++j) {
      uint4 v = hq2[j];
      if (j & 1) { DOT4(e1, wE[4 * j], wE[4 * j + 1], wE[4 * j + 2], wE[4 * j + 3], v); }
      else       { DOT4(e0, wE[4 * j], wE[4 * j + 1], wE[4 * j + 2], wE[4 * j + 3], v); }
    }
    float es = e0 + e1;
    es += __shfl_xor(es, 16);
    if (eh == 0) {
      float val = es + encbr;
      ctx[(size_t)bg * 64 + e] = (f16)val;
      s_ctx0[e] = val;
    }
  }
  __syncthreads();
  if (tid < 32) {
    float acc = qz0_b[tid];
#pragma unroll 8
    for (int k = 0; k < 64; ++k) acc += qz0_w[tid * 64 + k] * s_ctx0[k];
    s_q[tid] = acc;
  }
  __syncthreads();
  if (tid < 16) {
    float qm = s_q[tid], qls = s_q[16 + tid];
    float z0v = qm + __expf(qls) * z0_noise[bg * 16 + tid];
    z0_out[bg * 16 + tid] = z0v;
    float pm = pz0_mean[tid], pls = pz0_logstd[tid];
    float var_q = __expf(2.0f * qls);
    float var_p = __expf(2.0f * pls);
    float dm = qm - pm;
    float kl = pls - qls + (var_q + dm * dm) / (2.0f * var_p) - 0.5f;
    atomicAdd(&accums[5], kl);
  }
}

// ---------------------------------------------------------------------------
// Kernel 3: SDE scan. 512 blocks x 256 threads, 2 blocks/CU.
// R3 skeleton; 3 raw barriers/step; ctx in loop-carried register prefetch.
// A: tid<128 f1 row (z from LDS, ctx from regs) | tid>=128 h1 row + g-slice
// B: all 256 layer-2 full-K row
// CD (tid<64): layer-3 both MLPs (kh-split, shfl reduce) + g-combine + z upd
// ---------------------------------------------------------------------------
__global__ __launch_bounds__(256, 2) void k_sde(
    const f16* __restrict__ ctx, const float* __restrict__ z0_in,
    const float* __restrict__ ts, const float* __restrict__ bm_noise,
    const float* __restrict__ fw1, const float* __restrict__ fb1,
    const float* __restrict__ fw2, const float* __restrict__ fb2,
    const float* __restrict__ fw3, const float* __restrict__ fb3,
    const float* __restrict__ hw1, const float* __restrict__ hb1,
    const float* __restrict__ hw2, const float* __restrict__ hb2,
    const float* __restrict__ hw3, const float* __restrict__ hb3,
    const float* __restrict__ gw1, const float* __restrict__ gb1,
    const float* __restrict__ gw2, const float* __restrict__ gb2,
    f16* __restrict__ zs, float* __restrict__ accums) {
  __shared__ __align__(16) uint32_t s_x2z[8];   // z packed f16x2
  __shared__ float s_zf[16];                    // z f32
  __shared__ __align__(16) uint32_t s_h1f[64], s_h1h[64];
  __shared__ __align__(16) uint32_t s_h2f[64], s_h2h[64];
  __shared__ float s_gp[128];                   // [l][k8]
  __shared__ float s_dts[T_STEPS];

  const int tid = threadIdx.x;
  const int bg = blockIdx.x;
  const int lane = tid & 63;

  uint32_t uw[56];   // f1: 40 wpacks | h1: 8 wpacks + g: 48 f32-bits
  uint32_t wP2[64];  // layer-2 full row
  uint32_t w3[32];   // (tid<64) layer-3 K-half row
  float b1r = 0.f, b2r = 0.f, b3r = 0.f, gb2r = 0.f;

  if (tid < 128) {
    const float* w = fw1 + (size_t)tid * 80;
#pragma unroll
    for (int i = 0; i < 40; ++i) uw[i] = packh2(w[2 * i], w[2 * i + 1]);
    b1r = fb1[tid];
  } else {
    int u = tid - 128;
    const float* w = hw1 + (size_t)u * 16;
#pragma unroll
    for (int i = 0; i < 8; ++i) uw[i] = packh2(w[2 * i], w[2 * i + 1]);
    b1r = hb1[u];
    int l = u & 15, k8 = u >> 4;
#pragma unroll
    for (int i = 0; i < 16; ++i) {
      int h = k8 * 16 + i;
      uw[8 + i] = __builtin_bit_cast(uint32_t, gw1[l * 128 + h]);
      uw[24 + i] = __builtin_bit_cast(uint32_t, gb1[l * 128 + h]);
      uw[40 + i] = __builtin_bit_cast(uint32_t, gw2[l * 128 + h]);
    }
  }
  {
    int mlp = tid >> 7, u = tid & 127;
    const float* w = (mlp ? hw2 : fw2) + (size_t)u * 128;
#pragma unroll
    for (int i = 0; i < 64; ++i) wP2[i] = packh2(w[2 * i], w[2 * i + 1]);
    b2r = (mlp ? hb2 : fb2)[u];
  }
  if (tid < 64) {
    int mlp = lane >> 5, o = lane & 15, kh = (lane >> 4) & 1;
    const float* w = (mlp ? hw3 : fw3) + (size_t)o * 128 + kh * 64;
#pragma unroll
    for (int i = 0; i < 32; ++i) w3[i] = packh2(w[2 * i], w[2 * i + 1]);
    b3r = (mlp ? hb3 : fb3)[o];
    if (lane < 16) gb2r = gb2[lane];
  }
  for (int i = tid; i < T_STEPS - 1; i += 256) s_dts[i] = ts[i + 1] - ts[i];

  if (tid < 16) {
    float z = z0_in[bg * 16 + tid];
    s_zf[tid] = z;
    zs[(size_t)bg * 16 + tid] = (f16)z;
  }
  if (tid < 8)
    s_x2z[tid] = packh2(z0_in[bg * 16 + 2 * tid], z0_in[bg * 16 + 2 * tid + 1]);
  float bm_cur = 0.f;
  if (tid < 16) bm_cur = bm_noise[((size_t)0 * B_SZ + bg) * 16 + tid];
  uint4 cc[8];
  if (tid < 128) {
    const uint4* cr =
        (const uint4*)((const uint32_t*)ctx + ((size_t)1 * B_SZ + bg) * 32);
#pragma unroll
    for (int i = 0; i < 8; ++i) cc[i] = cr[i];
  }
  float path_acc = 0.0f;
  __syncthreads();

  for (int t = 0; t < T_STEPS - 1; ++t) {
    // ---- A: f1 (waves 0-1) | h1 + g (waves 2-3)
    if (tid < 128) {
      const uint4* zq = (const uint4*)s_x2z;
      uint4 zv0 = zq[0], zv1 = zq[1];
      float a0 = b1r, a1 = 0.f, a2 = 0.f, a3 = 0.f;
      DOT4(a0, uw[0], uw[1], uw[2], uw[3], zv0);
      DOT4(a1, uw[4], uw[5], uw[6], uw[7], zv1);
#pragma unroll
      for (int j = 0; j < 8; ++j) {
        uint4 v = cc[j];
        if (j & 1) { DOT4(a3, uw[8 + 4 * j], uw[9 + 4 * j], uw[10 + 4 * j], uw[11 + 4 * j], v); }
        else       { DOT4(a2, uw[8 + 4 * j], uw[9 + 4 * j], uw[10 + 4 * j], uw[11 + 4 * j], v); }
      }
      ((f16*)s_h1f)[tid] = (f16)softplusf_((a0 + a1) + (a2 + a3));
      if (t <= T_STEPS - 3) {  // refill ctx prefetch (in flight until next A)
        const uint4* cr = (const uint4*)((const uint32_t*)ctx +
                                         ((size_t)(t + 2) * B_SZ + bg) * 32);
#pragma unroll
        for (int i = 0; i < 8; ++i) cc[i] = cr[i];
      }
    } else {
      int u = tid - 128;
      const uint4* zq = (const uint4*)s_x2z;
      uint4 zv0 = zq[0], zv1 = zq[1];
      float a0 = b1r, a1 = 0.f;
      DOT4(a0, uw[0], uw[1], uw[2], uw[3], zv0);
      DOT4(a1, uw[4], uw[5], uw[6], uw[7], zv1);
      ((f16*)s_h1h)[u] = (f16)softplusf_(a0 + a1);
      int l = u & 15, k8 = u >> 4;
      float y = s_zf[l];
      float acc = 0.f;
#pragma unroll
      for (int i = 0; i < 16; ++i) {
        float pre = fmaf(y, __builtin_bit_cast(float, uw[8 + i]),
                         __builtin_bit_cast(float, uw[24 + i]));
        acc = fmaf(softplusf_(pre), __builtin_bit_cast(float, uw[40 + i]), acc);
      }
      s_gp[l * 8 + k8] = acc;
    }
    BAR_LDS();
    // ---- B: layer-2 full-K rows (all 256)
    {
      const uint4* hq = (const uint4*)((tid >> 7) ? s_h1h : s_h1f);
      float a0 = b2r, a1 = 0.f, a2 = 0.f, a3 = 0.f;
#pragma unroll
      for (int j = 0; j < 16; j += 4) {
        uint4 v0 = hq[j], v1 = hq[j + 1], v2 = hq[j + 2], v3 = hq[j + 3];
        DOT4(a0, wP2[4 * j], wP2[4 * j + 1], wP2[4 * j + 2], wP2[4 * j + 3], v0);
        DOT4(a1, wP2[4 * j + 4], wP2[4 * j + 5], wP2[4 * j + 6], wP2[4 * j + 7], v1);
        DOT4(a2, wP2[4 * j + 8], wP2[4 * j + 9], wP2[4 * j + 10], wP2[4 * j + 11], v2);
        DOT4(a3, wP2[4 * j + 12], wP2[4 * j + 13], wP2[4 * j + 14], wP2[4 * j + 15], v3);
      }
      f16* dst = (tid >> 7) ? (f16*)s_h2h : (f16*)s_h2f;
      dst[tid & 127] = (f16)softplusf_((a0 + a1) + (a2 + a3));
    }
    BAR_LDS();
    // ---- CD (wave 0 only): layer-3 both MLPs + g combine + z update
    if (tid < 64) {
      int mlp = lane >> 5, kh = (lane >> 4) & 1, o = lane & 15;
      const uint4* hq =
          (const uint4*)((mlp ? s_h2h : s_h2f) + kh * 32);
      uint4 v0 = hq[0], v1 = hq[1], v2 = hq[2], v3 = hq[3];
      uint4 v4 = hq[4], v5 = hq[5], v6 = hq[6], v7 = hq[7];
      float a0 = 0.f, a1 = 0.f;
      DOT4(a0, w3[0], w3[1], w3[2], w3[3], v0);
      DOT4(a1, w3[4], w3[5], w3[6], w3[7], v1);
      DOT4(a0, w3[8], w3[9], w3[10], w3[11], v2);
      DOT4(a1, w3[12], w3[13], w3[14], w3[15], v3);
      DOT4(a0, w3[16], w3[17], w3[18], w3[19], v4);
      DOT4(a1, w3[20], w3[21], w3[22], w3[23], v5);
      DOT4(a0, w3[24], w3[25], w3[26], w3[27], v6);
      DOT4(a1, w3[28], w3[29], w3[30], w3[31], v7);
      float v = a0 + a1;
      v += __shfl_xor(v, 16);  // combine kh halves
      float v3s = v + b3r;
      float other = __shfl_xor(v3s, 32);  // f <-> h exchange
      if (lane < 16) {
        float fv = v3s, hv = other;
        const float4* gp = (const float4*)&s_gp[o * 8];
        float4 g0 = gp[0], g1 = gp[1];
        float gv = sigmoidf_(gb2r + ((g0.x + g0.y) + (g0.z + g0.w)) +
                             ((g1.x + g1.y) + (g1.z + g1.w)));
        float dt = s_dts[t];
        float uu = (fv - hv) / gv;
        float lsum = uu * uu;
        lsum += __shfl_xor(lsum, 1);
        lsum += __shfl_xor(lsum, 2);
        lsum += __shfl_xor(lsum, 4);
        lsum += __shfl_xor(lsum, 8);
        if (o == 0) path_acc += 0.5f * lsum * dt;
        float zn = s_zf[o] + fv * dt + gv * (sqrtf(dt) * bm_cur);
        s_zf[o] = zn;
        zs[((size_t)(t + 1) * B_SZ + bg) * 16 + o] = (f16)zn;
        float zo = __shfl_xor(zn, 1);
        if (!(o & 1)) s_x2z[o >> 1] = packh2(zn, zo);
        if (t < T_STEPS - 2)
          bm_cur = bm_noise[((size_t)(t + 1) * B_SZ + bg) * 16 + o];
      }
    }
    BAR_LDS();
  }
  if (tid == 0) atomicAdd(&accums[6], path_acc);
}

// ---------------------------------------------------------------------------
// Kernel 4: decoder + losses.  2 tokens per thread, uint4 LDS layouts.
// ---------------------------------------------------------------------------
__global__ __launch_bounds__(256) void k_dec(
    const f16* __restrict__ zs, const f16* __restrict__ state_t,
    const float* __restrict__ xs, const float* __restrict__ proj_w,
    const float* __restrict__ proj_b, const float* __restrict__ act_w,
    const float* __restrict__ act_b, const float* __restrict__ land_w,
    const float* __restrict__ shot_w, const float* __restrict__ move_w,
    float* __restrict__ accums) {
  __shared__ __align__(16) uint32_t s_proj[32 * 8];
  __shared__ __align__(16) uint32_t s_act[128 * 8];
  __shared__ __align__(16) uint32_t s_head[128 * 8];
  __shared__ float s_pb[32], s_ab[128];
  __shared__ float s_red[4 * 5];

  const int tid = threadIdx.x;
  if (tid < 256) {
    int i = tid >> 3, kp = tid & 7;
    s_proj[tid] = packh2(proj_w[i * 16 + 2 * kp], proj_w[i * 16 + 2 * kp + 1]);
  }
  for (int id = tid; id < 1024; id += 256) {
    int j = id >> 3, kp = id & 7;
    s_act[id] = packh2(act_w[j * 16 + 2 * kp], act_w[j * 16 + 2 * kp + 1]);
  }
  for (int id = tid; id < 1024; id += 256) {
    int j = id >> 3, p = id & 7;
    int h0 = 2 * p, h1 = 2 * p + 1;
    float w0 = (h0 < 2) ? land_w[h0 * 128 + j]
                        : (h0 < 14 ? shot_w[(h0 - 2) * 128 + j]
                                   : move_w[(h0 - 14) * 128 + j]);
    float w1 = (h1 < 2) ? land_w[h1 * 128 + j]
                        : (h1 < 14 ? shot_w[(h1 - 2) * 128 + j]
                                   : move_w[(h1 - 14) * 128 + j]);
    s_head[j * 8 + p] = packh2(w0, w1);
  }
  if (tid < 32) s_pb[tid] = proj_b[tid];
  if (tid < 128) s_ab[tid] = act_b[tid];
  __syncthreads();

  size_t idx0 = (size_t)blockIdx.x * 512 + tid;
  size_t idx1 = idx0 + 256;
  uint32_t zA[8], zB[8];
  {
    const uint4* za = (const uint4*)(zs + idx0 * 16);
    const uint4* zb = (const uint4*)(zs + idx1 * 16);
    uint4 a0 = za[0], a1 = za[1], b0 = zb[0], b1 = zb[1];
    zA[0] = a0.x; zA[1] = a0.y; zA[2] = a0.z; zA[3] = a0.w;
    zA[4] = a1.x; zA[5] = a1.y; zA[6] = a1.z; zA[7] = a1.w;
    zB[0] = b0.x; zB[1] = b0.y; zB[2] = b0.z; zB[3] = b0.w;
    zB[4] = b1.x; zB[5] = b1.y; zB[6] = b1.z; zB[7] = b1.w;
  }
  uint32_t stA[16], stB[16];
  {
    const uint4* sa = (const uint4*)(state_t + idx0 * 32);
    const uint4* sb = (const uint4*)(state_t + idx1 * 32);
#pragma unroll
    for (int q = 0; q < 4; ++q) {
      uint4 va = sa[q], vb = sb[q];
      stA[4 * q] = va.x; stA[4 * q + 1] = va.y; stA[4 * q + 2] = va.z; stA[4 * q + 3] = va.w;
      stB[4 * q] = vb.x; stB[4 * q + 1] = vb.y; stB[4 * q + 2] = vb.z; stB[4 * q + 3] = vb.w;
    }
  }

  float sqA = 0.0f, sqB = 0.0f;
#pragma unroll 4
  for (int i = 0; i < 32; ++i) {
    const uint4* pw = (const uint4*)&s_proj[i * 8];
    uint4 w0 = pw[0], w1 = pw[1];
    float aA = s_pb[i], aB = s_pb[i];
    DOT4(aA, w0.x, w0.y, w0.z, w0.w, *(const uint4*)&zA[0]);
    DOT4(aA, w1.x, w1.y, w1.z, w1.w, *(const uint4*)&zA[4]);
    DOT4(aB, w0.x, w0.y, w0.z, w0.w, *(const uint4*)&zB[0]);
    DOT4(aB, w1.x, w1.y, w1.z, w1.w, *(const uint4*)&zB[4]);
    f16x2 svA = __builtin_bit_cast(f16x2, stA[i >> 1]);
    f16x2 svB = __builtin_bit_cast(f16x2, stB[i >> 1]);
    float dA = (float)svA[i & 1] - aA;
    float dB = (float)svB[i & 1] - aB;
    sqA += dA * dA;
    sqB += dB * dB;
  }

  float hdA[16], hdB[16];
#pragma unroll
  for (int i = 0; i < 16; ++i) { hdA[i] = 0.0f; hdB[i] = 0.0f; }
#pragma unroll 2
  for (int j = 0; j < 128; ++j) {
    const uint4* aw = (const uint4*)&s_act[j * 8];
    uint4 w0 = aw[0], w1 = aw[1];
    float aA = s_ab[j], aB = s_ab[j];
    DOT4(aA, w0.x, w0.y, w0.z, w0.w, *(const uint4*)&zA[0]);
    DOT4(aA, w1.x, w1.y, w1.z, w1.w, *(const uint4*)&zA[4]);
    DOT4(aB, w0.x, w0.y, w0.z, w0.w, *(const uint4*)&zB[0]);
    DOT4(aB, w1.x, w1.y, w1.z, w1.w, *(const uint4*)&zB[4]);
    aA = fmaxf(aA, 0.0f);
    aB = fmaxf(aB, 0.0f);
    const uint4* hw = (const uint4*)&s_head[j * 8];
    uint4 h0 = hw[0], h1 = hw[1];
    uint32_t whu[8] = {h0.x, h0.y, h0.z, h0.w, h1.x, h1.y, h1.z, h1.w};
#pragma unroll
    for (int p = 0; p < 8; ++p) {
      f16x2 w = __builtin_bit_cast(f16x2, whu[p]);
      float w0f = (float)w[0], w1f = (float)w[1];
      hdA[2 * p] += w0f * aA;
      hdA[2 * p + 1] += w1f * aA;
      hdB[2 * p] += w0f * aB;
      hdB[2 * p + 1] += w1f * aB;
    }
  }

  float vals[5] = {sqA + sqB, 0.f, 0.f, 0.f, 0.f};
#pragma unroll
  for (int tok = 0; tok < 2; ++tok) {
    const float* hd = tok ? hdB : hdA;
    const float* xp = xs + (tok ? idx1 : idx0) * 23;
    float dl0 = hd[0] - xp[18], dl1 = hd[1] - xp[19];
    vals[1] += dl0 * dl0 + dl1 * dl1;
    float dm0 = hd[14] - xp[21], dm1 = hd[15] - xp[22];
    vals[2] += dm0 * dm0 + dm1 * dm1;
    int sid = (int)xp[20];
    float m = hd[2];
#pragma unroll
    for (int s = 1; s < 12; ++s) m = fmaxf(m, hd[2 + s]);
    float sume = 0.0f;
#pragma unroll
    for (int s = 0; s < 12; ++s) sume += __expf(hd[2 + s] - m);
    float lse = m + __logf(sume);
    float pl = 0.0f;
#pragma unroll
    for (int s = 0; s < 12; ++s)
      if (s == sid) pl = hd[2 + s];
    if (sid != 0) {
      vals[3] += pl - lse;
      vals[4] += 1.0f;
    }
  }
#pragma unroll
  for (int v = 0; v < 5; ++v) {
    float x = vals[v];
    for (int off = 1; off < 64; off <<= 1) x += __shfl_xor(x, off);
    vals[v] = x;
  }
  int lane = tid & 63, wv = tid >> 6;
  if (lane == 0) {
#pragma unroll
    for (int v = 0; v < 5; ++v) s_red[wv * 5 + v] = vals[v];
  }
  __syncthreads();
  if (tid == 0) {
#pragma unroll
    for (int v = 0; v < 5; ++v) {
      float s = s_red[v] + s_red[5 + v] + s_red[10 + v] + s_red[15 + v];
      atomicAdd(&accums[v], s);
    }
  }
}

// ---------------------------------------------------------------------------
// Kernel 5: finalize the two scalar outputs.
// ---------------------------------------------------------------------------
__global__ void k_fin(const float* __restrict__ accums,
                      const float* __restrict__ noise_std,
                      float* __restrict__ out) {
  if (threadIdx.x == 0 && blockIdx.x == 0) {
    float sd = noise_std[0];
    float log_pxs = -0.5f * accums[0] / (sd * sd * (float)B_SZ) -
                    (float)T_STEPS * 32.0f * (logf(sd) + 0.5f * LOG2PI);
    float land = accums[1] / (float)(T_STEPS * B_SZ * 2);
    float move = accums[2] / (float)(T_STEPS * B_SZ * 2);
    float shot = -accums[3] / fmaxf(accums[4], 1.0f);
    float out1 = accums[5] / (float)B_SZ + accums[6] / (float)B_SZ + land + shot + move;
    out[0] = log_pxs;
    out[1] = out1;
  }
}

// ---------------------------------------------------------------------------
extern "C" void kernel_launch(void* const* d_in, const int* in_sizes, int n_in,
                              void* d_out, int out_size, void* d_ws,
                              size_t ws_size, hipStream_t stream) {
  const float* xs = (const float*)d_in[1];
  const float* ts = (const float*)d_in[2];
  const float* noise_std = (const float*)d_in[3];
  const float* z0_noise = (const float*)d_in[4];
  const float* bm_noise = (const float*)d_in[5];
  const float* shot_emb = (const float*)d_in[6];
  const float* player_emb = (const float*)d_in[7];
  const float* gru_wih = (const float*)d_in[8];
  const float* gru_whh = (const float*)d_in[9];
  const float* gru_bih = (const float*)d_in[10];
  const float* gru_bhh = (const float*)d_in[11];
  const float* enc_w = (const float*)d_in[12];
  const float* enc_b = (const float*)d_in[13];
  const float* qz0_w = (const float*)d_in[14];
  const float* qz0_b = (const float*)d_in[15];
  const float* f_w1 = (const float*)d_in[16];
  const float* f_b1 = (const float*)d_in[17];
  const float* f_w2 = (const float*)d_in[18];
  const float* f_b2 = (const float*)d_in[19];
  const float* f_w3 = (const float*)d_in[20];
  const float* f_b3 = (const float*)d_in[21];
  const float* h_w1 = (const float*)d_in[22];
  const float* h_b1 = (const float*)d_in[23];
  const float* h_w2 = (const float*)d_in[24];
  const float* h_b2 = (const float*)d_in[25];
  const float* h_w3 = (const float*)d_in[26];
  const float* h_b3 = (const float*)d_in[27];
  const float* g_w1 = (const float*)d_in[28];
  const float* g_b1 = (const float*)d_in[29];
  const float* g_w2 = (const float*)d_in[30];
  const float* g_b2 = (const float*)d_in[31];
  const float* proj_w = (const float*)d_in[32];
  const float* proj_b = (const float*)d_in[33];
  const float* pz0_mean = (const float*)d_in[34];
  const float* pz0_logstd = (const float*)d_in[35];
  const float* act_w = (const float*)d_in[36];
  const float* act_b = (const float*)d_in[37];
  const float* act_land_w = (const float*)d_in[38];
  const float* act_shot_w = (const float*)d_in[39];
  const float* act_move_w = (const float*)d_in[40];

  char* ws = (char*)d_ws;
  float* accums = (float*)ws;                       // 16 floats
  f16* state_t = (f16*)(ws + 256);                  // T*B*32 f16 = 16 MB
  f16* ctx = (f16*)(ws + 256 + 16777216);           // T*B*64 f16 = 32 MB
  float* z0b = (float*)(ws + 256 + 16777216 + 33554432);   // B*16 f32
  f16* zs = (f16*)(ws + 256 + 16777216 + 33554432 + 32768);  // T*B*16 f16 = 8 MB

  k_embed<<<1024, 256, 0, stream>>>(xs, shot_emb, player_emb, state_t, accums);
  k_gru<<<512, 256, 0, stream>>>(state_t, gru_wih, gru_whh, gru_bih, gru_bhh,
                                 enc_w, enc_b, qz0_w, qz0_b, z0_noise, pz0_mean,
                                 pz0_logstd, ctx, z0b, accums);
  k_sde<<<512, 256, 0, stream>>>(ctx, z0b, ts, bm_noise, f_w1, f_b1, f_w2, f_b2,
                                 f_w3, f_b3, h_w1, h_b1, h_w2, h_b2, h_w3, h_b3,
                                 g_w1, g_b1, g_w2, g_b2, zs, accums);
  k_dec<<<512, 256, 0, stream>>>(zs, state_t, xs, proj_w, proj_b, act_w, act_b,
                                 act_land_w, act_shot_w, act_move_w, accums);
  k_fin<<<1, 64, 0, stream>>>(accums, noise_std, (float*)d_out);
}

// Round 7
// 2138.765 us; speedup vs baseline: 2.8310x; 1.0038x over previous
//
#include <hip/hip_runtime.h>
#include <cstdint>

typedef _Float16 f16;
typedef _Float16 f16x2 __attribute__((ext_vector_type(2)));

#define T_STEPS 512
#define B_SZ 512
#define LOG2PI 1.8378770664093453f

// raw barrier: drain LDS counters only, never vmcnt (global ops stay in flight)
#define BAR_LDS() asm volatile("s_waitcnt lgkmcnt(0)\n\ts_barrier" ::: "memory")

__device__ __forceinline__ uint32_t packh2(float a, float b) {
  f16x2 v; v[0] = (f16)a; v[1] = (f16)b;
  return __builtin_bit_cast(uint32_t, v);
}

__device__ __forceinline__ float fdot2(uint32_t a, uint32_t b, float c) {
#if defined(__AMDGCN__) && __has_builtin(__builtin_amdgcn_fdot2)
  return __builtin_amdgcn_fdot2(__builtin_bit_cast(f16x2, a),
                                __builtin_bit_cast(f16x2, b), c, false);
#else
  f16x2 x = __builtin_bit_cast(f16x2, a), y = __builtin_bit_cast(f16x2, b);
  return c + (float)x[0] * (float)y[0] + (float)x[1] * (float)y[1];
#endif
}

#define DOT4(acc, w0, w1, w2, w3, v)                                     \
  do {                                                                   \
    acc = fdot2((w0), (v).x, acc); acc = fdot2((w1), (v).y, acc);        \
    acc = fdot2((w2), (v).z, acc); acc = fdot2((w3), (v).w, acc);        \
  } while (0)

__device__ __forceinline__ float sigmoidf_(float x) {
  return 1.0f / (1.0f + __expf(-x));
}
__device__ __forceinline__ float tanhf_(float x) {
  float ax = fabsf(x);
  float t = __expf(-2.0f * ax);
  float r = (1.0f - t) / (1.0f + t);
  return copysignf(r, x);
}
__device__ __forceinline__ float softplusf_(float x) {
  return fmaxf(x, 0.0f) + __logf(1.0f + __expf(-fabsf(x)));
}

// ---------------------------------------------------------------------------
// Kernel 1: embedding / state_t construction.  state_t: (T,B,32) f16.
// ---------------------------------------------------------------------------
__global__ __launch_bounds__(256) void k_embed(
    const float* __restrict__ xs, const float* __restrict__ shot_emb,
    const float* __restrict__ player_emb, f16* __restrict__ state_t,
    float* __restrict__ accums) {
  if (blockIdx.x == 0 && threadIdx.x < 16) accums[threadIdx.x] = 0.0f;
  size_t idx = (size_t)blockIdx.x * 256 + threadIdx.x;
  const float* xp = xs + idx * 23;
  f16* op = state_t + idx * 32;
  int sid = (int)xp[12];
  int pid = (int)xp[17];
#pragma unroll
  for (int i = 0; i < 12; ++i) op[i] = (f16)xp[i];
  const float* se = shot_emb + sid * 8;
#pragma unroll
  for (int i = 0; i < 8; ++i) op[12 + i] = (f16)se[i];
#pragma unroll
  for (int i = 0; i < 4; ++i) op[20 + i] = (f16)xp[13 + i];
  const float* pe = player_emb + pid * 8;
#pragma unroll
  for (int i = 0; i < 8; ++i) op[24 + i] = (f16)pe[i];
}

// ---------------------------------------------------------------------------
// Kernel 2: backward GRU scan + encoder + qz0 head.
// 512 blocks x 256 threads (4 waves), pinned 2 waves/EU (=> 256 VGPR budget,
// no spill: demand ~170). ONE raw barrier per step.
// ---------------------------------------------------------------------------
__global__ __launch_bounds__(256)
__attribute__((amdgpu_waves_per_eu(2, 2))) void k_gru(
    const f16* __restrict__ state_t, const float* __restrict__ wih,
    const float* __restrict__ whh, const float* __restrict__ bih,
    const float* __restrict__ bhh, const float* __restrict__ enc_w,
    const float* __restrict__ enc_b, const float* __restrict__ qz0_w,
    const float* __restrict__ qz0_b, const float* __restrict__ z0_noise,
    const float* __restrict__ pz0_mean, const float* __restrict__ pz0_logstd,
    f16* __restrict__ ctx, float* __restrict__ z0_out,
    float* __restrict__ accums) {
  __shared__ __align__(16) f16 s_hbuf[2][128];
  __shared__ float s_ctx0[64];
  __shared__ float s_q[32];

  const int tid = threadIdx.x;
  const int bg = blockIdx.x;
  const int lane = tid & 63;
  const int wid = tid >> 6;
  const int l31 = lane & 31;
  const int kh = lane >> 5;
  const int d = wid * 32 + l31;
  const int e = wid * 16 + (lane & 15);
  const int eh = (lane >> 4) & 1;
  const uint32_t* stu = (const uint32_t*)state_t;

  uint32_t wR[32], wZ[32], wN[32];
  uint32_t wXR[16], wXZ[16], wXN[16];
  uint32_t wE[32];
  float bR = 0.f, bZ = 0.f, bIN = 0.f, bHN = 0.f, encbr = 0.f;

  {
    const float* r = whh + (size_t)d * 128 + kh * 64;
#pragma unroll
    for (int i = 0; i < 32; ++i) wR[i] = packh2(r[2 * i], r[2 * i + 1]);
    r = whh + (size_t)(128 + d) * 128 + kh * 64;
#pragma unroll
    for (int i = 0; i < 32; ++i) wZ[i] = packh2(r[2 * i], r[2 * i + 1]);
    r = whh + (size_t)(256 + d) * 128 + kh * 64;
#pragma unroll
    for (int i = 0; i < 32; ++i) wN[i] = packh2(r[2 * i], r[2 * i + 1]);
  }
  if (kh == 0) {
    const float* r = wih + (size_t)d * 32;
#pragma unroll
    for (int i = 0; i < 16; ++i) wXR[i] = packh2(r[2 * i], r[2 * i + 1]);
    r = wih + (size_t)(128 + d) * 32;
#pragma unroll
    for (int i = 0; i < 16; ++i) wXZ[i] = packh2(r[2 * i], r[2 * i + 1]);
    r = wih + (size_t)(256 + d) * 32;
#pragma unroll
    for (int i = 0; i < 16; ++i) wXN[i] = packh2(r[2 * i], r[2 * i + 1]);
    bR = bih[d] + bhh[d];
    bZ = bih[128 + d] + bhh[128 + d];
    bIN = bih[256 + d];
    bHN = bhh[256 + d];
  } else {
    const float* r = enc_w + (size_t)e * 128 + eh * 64;
#pragma unroll
    for (int i = 0; i < 32; ++i) wE[i] = packh2(r[2 * i], r[2 * i + 1]);
    encbr = enc_b[e];
  }

  if (tid < 128) s_hbuf[0][tid] = (f16)0.0f;
  float h_old = 0.0f;
  __syncthreads();

  int cur = 0;
  uint4 xc0, xc1, xc2, xc3;
  {
    const uint4* xr = (const uint4*)(stu + ((size_t)(T_STEPS - 1) * B_SZ + bg) * 16);
    xc0 = xr[0]; xc1 = xr[1]; xc2 = xr[2]; xc3 = xr[3];
  }

  for (int t = T_STEPS - 1; t >= 0; --t) {
    uint4 xn0, xn1, xn2, xn3;
    if (t > 0) {
      const uint4* xr = (const uint4*)(stu + ((size_t)(t - 1) * B_SZ + bg) * 16);
      xn0 = xr[0]; xn1 = xr[1]; xn2 = xr[2]; xn3 = xr[3];
    }
    float aR = 0.f, aZ = 0.f, aIN = 0.f, aHN = 0.f;
    {
      const uint4* hq = (const uint4*)&s_hbuf[cur][kh * 64];
#pragma unroll
      for (int j = 0; j < 8; ++j) {
        uint4 v = hq[j];
        DOT4(aR, wR[4 * j], wR[4 * j + 1], wR[4 * j + 2], wR[4 * j + 3], v);
        DOT4(aZ, wZ[4 * j], wZ[4 * j + 1], wZ[4 * j + 2], wZ[4 * j + 3], v);
        DOT4(aHN, wN[4 * j], wN[4 * j + 1], wN[4 * j + 2], wN[4 * j + 3], v);
      }
    }
    float enc0 = 0.f, enc1 = 0.f;
    if (kh == 0) {
      DOT4(aR, wXR[0], wXR[1], wXR[2], wXR[3], xc0);
      DOT4(aR, wXR[4], wXR[5], wXR[6], wXR[7], xc1);
      DOT4(aR, wXR[8], wXR[9], wXR[10], wXR[11], xc2);
      DOT4(aR, wXR[12], wXR[13], wXR[14], wXR[15], xc3);
      DOT4(aZ, wXZ[0], wXZ[1], wXZ[2], wXZ[3], xc0);
      DOT4(aZ, wXZ[4], wXZ[5], wXZ[6], wXZ[7], xc1);
      DOT4(aZ, wXZ[8], wXZ[9], wXZ[10], wXZ[11], xc2);
      DOT4(aZ, wXZ[12], wXZ[13], wXZ[14], wXZ[15], xc3);
      DOT4(aIN, wXN[0], wXN[1], wXN[2], wXN[3], xc0);
      DOT4(aIN, wXN[4], wXN[5], wXN[6], wXN[7], xc1);
      DOT4(aIN, wXN[8], wXN[9], wXN[10], wXN[11], xc2);
      DOT4(aIN, wXN[12], wXN[13], wXN[14], wXN[15], xc3);
      aR += bR; aZ += bZ; aIN += bIN; aHN += bHN;
    } else if (t < T_STEPS - 1) {
      const uint4* hq2 = (const uint4*)&s_hbuf[cur][eh * 64];
#pragma unroll
      for (int j = 0; j < 8; ++j) {
        uint4 v = hq2[j];
        if (j & 1) { DOT4(enc1, wE[4 * j], wE[4 * j + 1], wE[4 * j + 2], wE[4 * j + 3], v); }
        else       { DOT4(enc0, wE[4 * j], wE[4 * j + 1], wE[4 * j + 2], wE[4 * j + 3], v); }
      }
    }
    aR += __shfl_xor(aR, 32);
    aZ += __shfl_xor(aZ, 32);
    aHN += __shfl_xor(aHN, 32);
    if (kh == 0) {
      float r = sigmoidf_(aR);
      float zg = sigmoidf_(aZ);
      float n = tanhf_(aIN + r * aHN);
      float hnew = (1.0f - zg) * n + zg * h_old;
      h_old = hnew;
      s_hbuf[cur ^ 1][d] = (f16)hnew;
    } else if (t < T_STEPS - 1) {
      float es = enc0 + enc1;
      es += __shfl_xor(es, 16);
      if (eh == 0)
        ctx[((size_t)(t + 1) * B_SZ + bg) * 64 + e] = (f16)(es + encbr);
    }
    BAR_LDS();
    cur ^= 1;
    if (t > 0) { xc0 = xn0; xc1 = xn1; xc2 = xn2; xc3 = xn3; }
  }

  if (kh == 1) {
    float e0 = 0.f, e1 = 0.f;
    const uint4* hq2 = (const uint4*)&s_hbuf[cur][eh * 64];
#pragma unroll
    for (int j = 0; j < 8; ++j) {
      uint4 v = hq2[j];
      if (j & 1) { DOT4(e1, wE[4 * j], wE[4 * j + 1], wE[4 * j + 2], wE[4 * j + 3], v); }
      else       { DOT4(e0, wE[4 * j], wE[4 * j + 1], wE[4 * j + 2], wE[4 * j + 3], v); }
    }
    float es = e0 + e1;
    es += __shfl_xor(es, 16);
    if (eh == 0) {
      float val = es + encbr;
      ctx[(size_t)bg * 64 + e] = (f16)val;
      s_ctx0[e] = val;
    }
  }
  __syncthreads();
  if (tid < 32) {
    float acc = qz0_b[tid];
#pragma unroll 8
    for (int k = 0; k < 64; ++k) acc += qz0_w[tid * 64 + k] * s_ctx0[k];
    s_q[tid] = acc;
  }
  __syncthreads();
  if (tid < 16) {
    float qm = s_q[tid], qls = s_q[16 + tid];
    float z0v = qm + __expf(qls) * z0_noise[bg * 16 + tid];
    z0_out[bg * 16 + tid] = z0v;
    float pm = pz0_mean[tid], pls = pz0_logstd[tid];
    float var_q = __expf(2.0f * qls);
    float var_p = __expf(2.0f * pls);
    float dm = qm - pm;
    float kl = pls - qls + (var_q + dm * dm) / (2.0f * var_p) - 0.5f;
    atomicAdd(&accums[5], kl);
  }
}

// ---------------------------------------------------------------------------
// Kernel 3: SDE scan. 512 blocks x 256 threads, pinned 2 waves/EU (=> 256
// VGPR budget; static demand ~190, no spill). 3 raw barriers/step.
// A: tid<128 f1 row (z from LDS, ctx from regs) | tid>=128 h1 row + g-slice
// B: all 256 layer-2 full-K row
// CD (tid<64): layer-3 both MLPs (kh-split, shfl reduce) + g-combine + z upd
// ---------------------------------------------------------------------------
__global__ __launch_bounds__(256)
__attribute__((amdgpu_waves_per_eu(2, 2))) void k_sde(
    const f16* __restrict__ ctx, const float* __restrict__ z0_in,
    const float* __restrict__ ts, const float* __restrict__ bm_noise,
    const float* __restrict__ fw1, const float* __restrict__ fb1,
    const float* __restrict__ fw2, const float* __restrict__ fb2,
    const float* __restrict__ fw3, const float* __restrict__ fb3,
    const float* __restrict__ hw1, const float* __restrict__ hb1,
    const float* __restrict__ hw2, const float* __restrict__ hb2,
    const float* __restrict__ hw3, const float* __restrict__ hb3,
    const float* __restrict__ gw1, const float* __restrict__ gb1,
    const float* __restrict__ gw2, const float* __restrict__ gb2,
    f16* __restrict__ zs, float* __restrict__ accums) {
  __shared__ __align__(16) uint32_t s_x2z[8];   // z packed f16x2
  __shared__ float s_zf[16];                    // z f32
  __shared__ __align__(16) uint32_t s_h1f[64], s_h1h[64];
  __shared__ __align__(16) uint32_t s_h2f[64], s_h2h[64];
  __shared__ float s_gp[128];                   // [l][k8]
  __shared__ float s_dts[T_STEPS];

  const int tid = threadIdx.x;
  const int bg = blockIdx.x;
  const int lane = tid & 63;

  uint32_t uw[56];   // f1: 40 wpacks | h1: 8 wpacks + g: 48 f32-bits
  uint32_t wP2[64];  // layer-2 full row
  uint32_t w3[32];   // (tid<64) layer-3 K-half row
  float b1r = 0.f, b2r = 0.f, b3r = 0.f, gb2r = 0.f;

  if (tid < 128) {
    const float* w = fw1 + (size_t)tid * 80;
#pragma unroll
    for (int i = 0; i < 40; ++i) uw[i] = packh2(w[2 * i], w[2 * i + 1]);
    b1r = fb1[tid];
  } else {
    int u = tid - 128;
    const float* w = hw1 + (size_t)u * 16;
#pragma unroll
    for (int i = 0; i < 8; ++i) uw[i] = packh2(w[2 * i], w[2 * i + 1]);
    b1r = hb1[u];
    int l = u & 15, k8 = u >> 4;
#pragma unroll
    for (int i = 0; i < 16; ++i) {
      int h = k8 * 16 + i;
      uw[8 + i] = __builtin_bit_cast(uint32_t, gw1[l * 128 + h]);
      uw[24 + i] = __builtin_bit_cast(uint32_t, gb1[l * 128 + h]);
      uw[40 + i] = __builtin_bit_cast(uint32_t, gw2[l * 128 + h]);
    }
  }
  {
    int mlp = tid >> 7, u = tid & 127;
    const float* w = (mlp ? hw2 : fw2) + (size_t)u * 128;
#pragma unroll
    for (int i = 0; i < 64; ++i) wP2[i] = packh2(w[2 * i], w[2 * i + 1]);
    b2r = (mlp ? hb2 : fb2)[u];
  }
  if (tid < 64) {
    int mlp = lane >> 5, o = lane & 15, kh = (lane >> 4) & 1;
    const float* w = (mlp ? hw3 : fw3) + (size_t)o * 128 + kh * 64;
#pragma unroll
    for (int i = 0; i < 32; ++i) w3[i] = packh2(w[2 * i], w[2 * i + 1]);
    b3r = (mlp ? hb3 : fb3)[o];
    if (lane < 16) gb2r = gb2[lane];
  }
  for (int i = tid; i < T_STEPS - 1; i += 256) s_dts[i] = ts[i + 1] - ts[i];

  if (tid < 16) {
    float z = z0_in[bg * 16 + tid];
    s_zf[tid] = z;
    zs[(size_t)bg * 16 + tid] = (f16)z;
  }
  if (tid < 8)
    s_x2z[tid] = packh2(z0_in[bg * 16 + 2 * tid], z0_in[bg * 16 + 2 * tid + 1]);
  float bm_cur = 0.f;
  if (tid < 16) bm_cur = bm_noise[((size_t)0 * B_SZ + bg) * 16 + tid];
  uint4 cc[8];
  if (tid < 128) {
    const uint4* cr =
        (const uint4*)((const uint32_t*)ctx + ((size_t)1 * B_SZ + bg) * 32);
#pragma unroll
    for (int i = 0; i < 8; ++i) cc[i] = cr[i];
  }
  float path_acc = 0.0f;
  __syncthreads();

  for (int t = 0; t < T_STEPS - 1; ++t) {
    // ---- A: f1 (waves 0-1) | h1 + g (waves 2-3)
    if (tid < 128) {
      const uint4* zq = (const uint4*)s_x2z;
      uint4 zv0 = zq[0], zv1 = zq[1];
      float a0 = b1r, a1 = 0.f, a2 = 0.f, a3 = 0.f;
      DOT4(a0, uw[0], uw[1], uw[2], uw[3], zv0);
      DOT4(a1, uw[4], uw[5], uw[6], uw[7], zv1);
#pragma unroll
      for (int j = 0; j < 8; ++j) {
        uint4 v = cc[j];
        if (j & 1) { DOT4(a3, uw[8 + 4 * j], uw[9 + 4 * j], uw[10 + 4 * j], uw[11 + 4 * j], v); }
        else       { DOT4(a2, uw[8 + 4 * j], uw[9 + 4 * j], uw[10 + 4 * j], uw[11 + 4 * j], v); }
      }
      ((f16*)s_h1f)[tid] = (f16)softplusf_((a0 + a1) + (a2 + a3));
      if (t <= T_STEPS - 3) {  // refill ctx prefetch (in flight until next A)
        const uint4* cr = (const uint4*)((const uint32_t*)ctx +
                                         ((size_t)(t + 2) * B_SZ + bg) * 32);
#pragma unroll
        for (int i = 0; i < 8; ++i) cc[i] = cr[i];
      }
    } else {
      int u = tid - 128;
      const uint4* zq = (const uint4*)s_x2z;
      uint4 zv0 = zq[0], zv1 = zq[1];
      float a0 = b1r, a1 = 0.f;
      DOT4(a0, uw[0], uw[1], uw[2], uw[3], zv0);
      DOT4(a1, uw[4], uw[5], uw[6], uw[7], zv1);
      ((f16*)s_h1h)[u] = (f16)softplusf_(a0 + a1);
      int l = u & 15, k8 = u >> 4;
      float y = s_zf[l];
      float acc = 0.f;
#pragma unroll
      for (int i = 0; i < 16; ++i) {
        float pre = fmaf(y, __builtin_bit_cast(float, uw[8 + i]),
                         __builtin_bit_cast(float, uw[24 + i]));
        acc = fmaf(softplusf_(pre), __builtin_bit_cast(float, uw[40 + i]), acc);
      }
      s_gp[l * 8 + k8] = acc;
    }
    BAR_LDS();
    // ---- B: layer-2 full-K rows (all 256)
    {
      const uint4* hq = (const uint4*)((tid >> 7) ? s_h1h : s_h1f);
      float a0 = b2r, a1 = 0.f, a2 = 0.f, a3 = 0.f;
#pragma unroll
      for (int j = 0; j < 16; j += 4) {
        uint4 v0 = hq[j], v1 = hq[j + 1], v2 = hq[j + 2], v3 = hq[j + 3];
        DOT4(a0, wP2[4 * j], wP2[4 * j + 1], wP2[4 * j + 2], wP2[4 * j + 3], v0);
        DOT4(a1, wP2[4 * j + 4], wP2[4 * j + 5], wP2[4 * j + 6], wP2[4 * j + 7], v1);
        DOT4(a2, wP2[4 * j + 8], wP2[4 * j + 9], wP2[4 * j + 10], wP2[4 * j + 11], v2);
        DOT4(a3, wP2[4 * j + 12], wP2[4 * j + 13], wP2[4 * j + 14], wP2[4 * j + 15], v3);
      }
      f16* dst = (tid >> 7) ? (f16*)s_h2h : (f16*)s_h2f;
      dst[tid & 127] = (f16)softplusf_((a0 + a1) + (a2 + a3));
    }
    BAR_LDS();
    // ---- CD (wave 0 only): layer-3 both MLPs + g combine + z update
    if (tid < 64) {
      int mlp = lane >> 5, kh = (lane >> 4) & 1, o = lane & 15;
      const uint4* hq =
          (const uint4*)((mlp ? s_h2h : s_h2f) + kh * 32);
      uint4 v0 = hq[0], v1 = hq[1], v2 = hq[2], v3 = hq[3];
      uint4 v4 = hq[4], v5 = hq[5], v6 = hq[6], v7 = hq[7];
      float a0 = 0.f, a1 = 0.f;
      DOT4(a0, w3[0], w3[1], w3[2], w3[3], v0);
      DOT4(a1, w3[4], w3[5], w3[6], w3[7], v1);
      DOT4(a0, w3[8], w3[9], w3[10], w3[11], v2);
      DOT4(a1, w3[12], w3[13], w3[14], w3[15], v3);
      DOT4(a0, w3[16], w3[17], w3[18], w3[19], v4);
      DOT4(a1, w3[20], w3[21], w3[22], w3[23], v5);
      DOT4(a0, w3[24], w3[25], w3[26], w3[27], v6);
      DOT4(a1, w3[28], w3[29], w3[30], w3[31], v7);
      float v = a0 + a1;
      v += __shfl_xor(v, 16);  // combine kh halves
      float v3s = v + b3r;
      float other = __shfl_xor(v3s, 32);  // f <-> h exchange
      if (lane < 16) {
        float fv = v3s, hv = other;
        const float4* gp = (const float4*)&s_gp[o * 8];
        float4 g0 = gp[0], g1 = gp[1];
        float gv = sigmoidf_(gb2r + ((g0.x + g0.y) + (g0.z + g0.w)) +
                             ((g1.x + g1.y) + (g1.z + g1.w)));
        float dt = s_dts[t];
        float uu = (fv - hv) / gv;
        float lsum = uu * uu;
        lsum += __shfl_xor(lsum, 1);
        lsum += __shfl_xor(lsum, 2);
        lsum += __shfl_xor(lsum, 4);
        lsum += __shfl_xor(lsum, 8);
        if (o == 0) path_acc += 0.5f * lsum * dt;
        float zn = s_zf[o] + fv * dt + gv * (sqrtf(dt) * bm_cur);
        s_zf[o] = zn;
        zs[((size_t)(t + 1) * B_SZ + bg) * 16 + o] = (f16)zn;
        float zo = __shfl_xor(zn, 1);
        if (!(o & 1)) s_x2z[o >> 1] = packh2(zn, zo);
        if (t < T_STEPS - 2)
          bm_cur = bm_noise[((size_t)(t + 1) * B_SZ + bg) * 16 + o];
      }
    }
    BAR_LDS();
  }
  if (tid == 0) atomicAdd(&accums[6], path_acc);
}

// ---------------------------------------------------------------------------
// Kernel 4: decoder + losses.  2 tokens per thread, uint4 LDS layouts.
// ---------------------------------------------------------------------------
__global__ __launch_bounds__(256) void k_dec(
    const f16* __restrict__ zs, const f16* __restrict__ state_t,
    const float* __restrict__ xs, const float* __restrict__ proj_w,
    const float* __restrict__ proj_b, const float* __restrict__ act_w,
    const float* __restrict__ act_b, const float* __restrict__ land_w,
    const float* __restrict__ shot_w, const float* __restrict__ move_w,
    float* __restrict__ accums) {
  __shared__ __align__(16) uint32_t s_proj[32 * 8];
  __shared__ __align__(16) uint32_t s_act[128 * 8];
  __shared__ __align__(16) uint32_t s_head[128 * 8];
  __shared__ float s_pb[32], s_ab[128];
  __shared__ float s_red[4 * 5];

  const int tid = threadIdx.x;
  if (tid < 256) {
    int i = tid >> 3, kp = tid & 7;
    s_proj[tid] = packh2(proj_w[i * 16 + 2 * kp], proj_w[i * 16 + 2 * kp + 1]);
  }
  for (int id = tid; id < 1024; id += 256) {
    int j = id >> 3, kp = id & 7;
    s_act[id] = packh2(act_w[j * 16 + 2 * kp], act_w[j * 16 + 2 * kp + 1]);
  }
  for (int id = tid; id < 1024; id += 256) {
    int j = id >> 3, p = id & 7;
    int h0 = 2 * p, h1 = 2 * p + 1;
    float w0 = (h0 < 2) ? land_w[h0 * 128 + j]
                        : (h0 < 14 ? shot_w[(h0 - 2) * 128 + j]
                                   : move_w[(h0 - 14) * 128 + j]);
    float w1 = (h1 < 2) ? land_w[h1 * 128 + j]
                        : (h1 < 14 ? shot_w[(h1 - 2) * 128 + j]
                                   : move_w[(h1 - 14) * 128 + j]);
    s_head[j * 8 + p] = packh2(w0, w1);
  }
  if (tid < 32) s_pb[tid] = proj_b[tid];
  if (tid < 128) s_ab[tid] = act_b[tid];
  __syncthreads();

  size_t idx0 = (size_t)blockIdx.x * 512 + tid;
  size_t idx1 = idx0 + 256;
  uint32_t zA[8], zB[8];
  {
    const uint4* za = (const uint4*)(zs + idx0 * 16);
    const uint4* zb = (const uint4*)(zs + idx1 * 16);
    uint4 a0 = za[0], a1 = za[1], b0 = zb[0], b1 = zb[1];
    zA[0] = a0.x; zA[1] = a0.y; zA[2] = a0.z; zA[3] = a0.w;
    zA[4] = a1.x; zA[5] = a1.y; zA[6] = a1.z; zA[7] = a1.w;
    zB[0] = b0.x; zB[1] = b0.y; zB[2] = b0.z; zB[3] = b0.w;
    zB[4] = b1.x; zB[5] = b1.y; zB[6] = b1.z; zB[7] = b1.w;
  }
  uint32_t stA[16], stB[16];
  {
    const uint4* sa = (const uint4*)(state_t + idx0 * 32);
    const uint4* sb = (const uint4*)(state_t + idx1 * 32);
#pragma unroll
    for (int q = 0; q < 4; ++q) {
      uint4 va = sa[q], vb = sb[q];
      stA[4 * q] = va.x; stA[4 * q + 1] = va.y; stA[4 * q + 2] = va.z; stA[4 * q + 3] = va.w;
      stB[4 * q] = vb.x; stB[4 * q + 1] = vb.y; stB[4 * q + 2] = vb.z; stB[4 * q + 3] = vb.w;
    }
  }

  float sqA = 0.0f, sqB = 0.0f;
#pragma unroll 4
  for (int i = 0; i < 32; ++i) {
    const uint4* pw = (const uint4*)&s_proj[i * 8];
    uint4 w0 = pw[0], w1 = pw[1];
    float aA = s_pb[i], aB = s_pb[i];
    DOT4(aA, w0.x, w0.y, w0.z, w0.w, *(const uint4*)&zA[0]);
    DOT4(aA, w1.x, w1.y, w1.z, w1.w, *(const uint4*)&zA[4]);
    DOT4(aB, w0.x, w0.y, w0.z, w0.w, *(const uint4*)&zB[0]);
    DOT4(aB, w1.x, w1.y, w1.z, w1.w, *(const uint4*)&zB[4]);
    f16x2 svA = __builtin_bit_cast(f16x2, stA[i >> 1]);
    f16x2 svB = __builtin_bit_cast(f16x2, stB[i >> 1]);
    float dA = (float)svA[i & 1] - aA;
    float dB = (float)svB[i & 1] - aB;
    sqA += dA * dA;
    sqB += dB * dB;
  }

  float hdA[16], hdB[16];
#pragma unroll
  for (int i = 0; i < 16; ++i) { hdA[i] = 0.0f; hdB[i] = 0.0f; }
#pragma unroll 2
  for (int j = 0; j < 128; ++j) {
    const uint4* aw = (const uint4*)&s_act[j * 8];
    uint4 w0 = aw[0], w1 = aw[1];
    float aA = s_ab[j], aB = s_ab[j];
    DOT4(aA, w0.x, w0.y, w0.z, w0.w, *(const uint4*)&zA[0]);
    DOT4(aA, w1.x, w1.y, w1.z, w1.w, *(const uint4*)&zA[4]);
    DOT4(aB, w0.x, w0.y, w0.z, w0.w, *(const uint4*)&zB[0]);
    DOT4(aB, w1.x, w1.y, w1.z, w1.w, *(const uint4*)&zB[4]);
    aA = fmaxf(aA, 0.0f);
    aB = fmaxf(aB, 0.0f);
    const uint4* hw = (const uint4*)&s_head[j * 8];
    uint4 h0 = hw[0], h1 = hw[1];
    uint32_t whu[8] = {h0.x, h0.y, h0.z, h0.w, h1.x, h1.y, h1.z, h1.w};
#pragma unroll
    for (int p = 0; p < 8; ++p) {
      f16x2 w = __builtin_bit_cast(f16x2, whu[p]);
      float w0f = (float)w[0], w1f = (float)w[1];
      hdA[2 * p] += w0f * aA;
      hdA[2 * p + 1] += w1f * aA;
      hdB[2 * p] += w0f * aB;
      hdB[2 * p + 1] += w1f * aB;
    }
  }

  float vals[5] = {sqA + sqB, 0.f, 0.f, 0.f, 0.f};
#pragma unroll
  for (int tok = 0; tok < 2; ++tok) {
    const float* hd = tok ? hdB : hdA;
    const float* xp = xs + (tok ? idx1 : idx0) * 23;
    float dl0 = hd[0] - xp[18], dl1 = hd[1] - xp[19];
    vals[1] += dl0 * dl0 + dl1 * dl1;
    float dm0 = hd[14] - xp[21], dm1 = hd[15] - xp[22];
    vals[2] += dm0 * dm0 + dm1 * dm1;
    int sid = (int)xp[20];
    float m = hd[2];
#pragma unroll
    for (int s = 1; s < 12; ++s) m = fmaxf(m, hd[2 + s]);
    float sume = 0.0f;
#pragma unroll
    for (int s = 0; s < 12; ++s) sume += __expf(hd[2 + s] - m);
    float lse = m + __logf(sume);
    float pl = 0.0f;
#pragma unroll
    for (int s = 0; s < 12; ++s)
      if (s == sid) pl = hd[2 + s];
    if (sid != 0) {
      vals[3] += pl - lse;
      vals[4] += 1.0f;
    }
  }
#pragma unroll
  for (int v = 0; v < 5; ++v) {
    float x = vals[v];
    for (int off = 1; off < 64; off <<= 1) x += __shfl_xor(x, off);
    vals[v] = x;
  }
  int lane = tid & 63, wv = tid >> 6;
  if (lane == 0) {
#pragma unroll
    for (int v = 0; v < 5; ++v) s_red[wv * 5 + v] = vals[v];
  }
  __syncthreads();
  if (tid == 0) {
#pragma unroll
    for (int v = 0; v < 5; ++v) {
      float s = s_red[v] + s_red[5 + v] + s_red[10 + v] + s_red[15 + v];
      atomicAdd(&accums[v], s);
    }
  }
}

// ---------------------------------------------------------------------------
// Kernel 5: finalize the two scalar outputs.
// ---------------------------------------------------------------------------
__global__ void k_fin(const float* __restrict__ accums,
                      const float* __restrict__ noise_std,
                      float* __restrict__ out) {
  if (threadIdx.x == 0 && blockIdx.x == 0) {
    float sd = noise_std[0];
    float log_pxs = -0.5f * accums[0] / (sd * sd * (float)B_SZ) -
                    (float)T_STEPS * 32.0f * (logf(sd) + 0.5f * LOG2PI);
    float land = accums[1] / (float)(T_STEPS * B_SZ * 2);
    float move = accums[2] / (float)(T_STEPS * B_SZ * 2);
    float shot = -accums[3] / fmaxf(accums[4], 1.0f);
    float out1 = accums[5] / (float)B_SZ + accums[6] / (float)B_SZ + land + shot + move;
    out[0] = log_pxs;
    out[1] = out1;
  }
}

// ---------------------------------------------------------------------------
extern "C" void kernel_launch(void* const* d_in, const int* in_sizes, int n_in,
                              void* d_out, int out_size, void* d_ws,
                              size_t ws_size, hipStream_t stream) {
  const float* xs = (const float*)d_in[1];
  const float* ts = (const float*)d_in[2];
  const float* noise_std = (const float*)d_in[3];
  const float* z0_noise = (const float*)d_in[4];
  const float* bm_noise = (const float*)d_in[5];
  const float* shot_emb = (const float*)d_in[6];
  const float* player_emb = (const float*)d_in[7];
  const float* gru_wih = (const float*)d_in[8];
  const float* gru_whh = (const float*)d_in[9];
  const float* gru_bih = (const float*)d_in[10];
  const float* gru_bhh = (const float*)d_in[11];
  const float* enc_w = (const float*)d_in[12];
  const float* enc_b = (const float*)d_in[13];
  const float* qz0_w = (const float*)d_in[14];
  const float* qz0_b = (const float*)d_in[15];
  const float* f_w1 = (const float*)d_in[16];
  const float* f_b1 = (const float*)d_in[17];
  const float* f_w2 = (const float*)d_in[18];
  const float* f_b2 = (const float*)d_in[19];
  const float* f_w3 = (const float*)d_in[20];
  const float* f_b3 = (const float*)d_in[21];
  const float* h_w1 = (const float*)d_in[22];
  const float* h_b1 = (const float*)d_in[23];
  const float* h_w2 = (const float*)d_in[24];
  const float* h_b2 = (const float*)d_in[25];
  const float* h_w3 = (const float*)d_in[26];
  const float* h_b3 = (const float*)d_in[27];
  const float* g_w1 = (const float*)d_in[28];
  const float* g_b1 = (const float*)d_in[29];
  const float* g_w2 = (const float*)d_in[30];
  const float* g_b2 = (const float*)d_in[31];
  const float* proj_w = (const float*)d_in[32];
  const float* proj_b = (const float*)d_in[33];
  const float* pz0_mean = (const float*)d_in[34];
  const float* pz0_logstd = (const float*)d_in[35];
  const float* act_w = (const float*)d_in[36];
  const float* act_b = (const float*)d_in[37];
  const float* act_land_w = (const float*)d_in[38];
  const float* act_shot_w = (const float*)d_in[39];
  const float* act_move_w = (const float*)d_in[40];

  char* ws = (char*)d_ws;
  float* accums = (float*)ws;                       // 16 floats
  f16* state_t = (f16*)(ws + 256);                  // T*B*32 f16 = 16 MB
  f16* ctx = (f16*)(ws + 256 + 16777216);           // T*B*64 f16 = 32 MB
  float* z0b = (float*)(ws + 256 + 16777216 + 33554432);   // B*16 f32
  f16* zs = (f16*)(ws + 256 + 16777216 + 33554432 + 32768);  // T*B*16 f16 = 8 MB

  k_embed<<<1024, 256, 0, stream>>>(xs, shot_emb, player_emb, state_t, accums);
  k_gru<<<512, 256, 0, stream>>>(state_t, gru_wih, gru_whh, gru_bih, gru_bhh,
                                 enc_w, enc_b, qz0_w, qz0_b, z0_noise, pz0_mean,
                                 pz0_logstd, ctx, z0b, accums);
  k_sde<<<512, 256, 0, stream>>>(ctx, z0b, ts, bm_noise, f_w1, f_b1, f_w2, f_b2,
                                 f_w3, f_b3, h_w1, h_b1, h_w2, h_b2, h_w3, h_b3,
                                 g_w1, g_b1, g_w2, g_b2, zs, accums);
  k_dec<<<512, 256, 0, stream>>>(zs, state_t, xs, proj_w, proj_b, act_w, act_b,
                                 act_land_w, act_shot_w, act_move_w, accums);
  k_fin<<<1, 64, 0, stream>>>(accums, noise_std, (float*)d_out);
}